// Round 8
// baseline (13331.653 us; speedup 1.0000x reference)
//
#include <hip/hip_runtime.h>
#include <cstdint>
#include <cstddef>

#define MINN 1e-15f
#define EPSA 1e-7f
#define C_L2E 1.44269504088896341f
#define C_LN2 0.69314718055994531f

typedef _Float16 half_t;
typedef _Float16 half2_t __attribute__((ext_vector_type(2)));

#if defined(__has_builtin)
#if __has_builtin(__builtin_amdgcn_update_dpp) && __has_builtin(__builtin_amdgcn_readlane)
#define USE_DPP 1
#endif
#endif

// ---------- fast-math helpers (native, ~1 ulp) ----------
__device__ __forceinline__ float fexp2_(float x) {
#if defined(__has_builtin) && __has_builtin(__builtin_amdgcn_exp2f)
    return __builtin_amdgcn_exp2f(x);
#else
    return exp2f(x);
#endif
}
__device__ __forceinline__ float flog2_(float x) {
#if defined(__has_builtin) && __has_builtin(__builtin_amdgcn_logf)
    return __builtin_amdgcn_logf(x);
#else
    return log2f(x);
#endif
}
__device__ __forceinline__ float frcp_(float x) {
#if defined(__has_builtin) && __has_builtin(__builtin_amdgcn_rcpf)
    return __builtin_amdgcn_rcpf(x);
#else
    return 1.f / x;
#endif
}
__device__ __forceinline__ float tan_k_(float u, float sk, float rsk) {
    float a = fminf(fmaxf(sk * u, -15.f), 15.f);
    float t = fexp2_(a * (2.f * C_L2E));
    return (1.f - 2.f * frcp_(t + 1.f)) * rsk;
}
__device__ __forceinline__ float artan_k_(float u, float sk, float rsk) {
    float a = fminf(fmaxf(sk * u, -1.f + EPSA), 1.f - EPSA);
    return flog2_((1.f + a) * frcp_(1.f - a)) * (0.5f * C_LN2) * rsk;
}
__device__ __forceinline__ float sigm_(float x) {
    return frcp_(1.f + fexp2_(-x * C_L2E));
}
__device__ __forceinline__ float wave_sum(float v) {
#pragma unroll
    for (int off = 32; off; off >>= 1) v += __shfl_xor(v, off, 64);
    return v;
}

// ---------- DPP reduction primitives (VALU pipe, not DS) ----------
#ifdef USE_DPP
template <int CTRL, int RM, int BM>
__device__ __forceinline__ float dppmov_(float x) {
    return __builtin_bit_cast(float,
        __builtin_amdgcn_update_dpp(0, __builtin_bit_cast(int, x), CTRL, RM, BM, false));
}
#endif
// full 64-lane sum; result valid in lane 63 (fallback: all lanes)
__device__ __forceinline__ float wsum63_(float x) {
#ifdef USE_DPP
    x += dppmov_<0x111, 0xf, 0xf>(x);  // row_shr:1
    x += dppmov_<0x112, 0xf, 0xf>(x);  // row_shr:2
    x += dppmov_<0x114, 0xf, 0xe>(x);  // row_shr:4
    x += dppmov_<0x118, 0xf, 0xc>(x);  // row_shr:8  -> lane15 of each row
    x += dppmov_<0x142, 0xa, 0xf>(x);  // row_bcast:15
    x += dppmov_<0x143, 0xc, 0xf>(x);  // row_bcast:31 -> lane63 = total
    return x;
#else
    return wave_sum(x);
#endif
}
// 16-lane row sum; result valid in lane 16k+15 (fallback: all lanes)
__device__ __forceinline__ float gsum16_(float x) {
#ifdef USE_DPP
    x += dppmov_<0x111, 0xf, 0xf>(x);
    x += dppmov_<0x112, 0xf, 0xf>(x);
    x += dppmov_<0x114, 0xf, 0xe>(x);
    x += dppmov_<0x118, 0xf, 0xc>(x);
    return x;
#else
    x += __shfl_xor(x, 1, 64);
    x += __shfl_xor(x, 2, 64);
    x += __shfl_xor(x, 4, 64);
    x += __shfl_xor(x, 8, 64);
    return x;
#endif
}
__device__ __forceinline__ float rdlane_(float x, int l) {
#ifdef USE_DPP
    return __builtin_bit_cast(float,
        __builtin_amdgcn_readlane(__builtin_bit_cast(int, x), l));
#else
    return __shfl(x, l, 64);
#endif
}
// block(1024,16-wave) reduce of N values (N in {2,4,8}); ONE internal barrier.
// redbuf needs 16*N floats (<=128). Caller alternates buffers.
template <int N>
__device__ __forceinline__ void bredX(float* v, float* redbuf, int tid) {
    const int lane = tid & 63, wave = tid >> 6;
#pragma unroll
    for (int n = 0; n < N; ++n) {
        float s = wsum63_(v[n]);
        if (lane == 63) redbuf[n * 16 + wave] = s;
    }
    __syncthreads();
    if (N <= 4) {
        float part = gsum16_(redbuf[lane & (16 * N - 1)]);
#pragma unroll
        for (int n = 0; n < N; ++n) v[n] = rdlane_(part, 16 * n + 15);
    } else {
        float part0 = gsum16_(redbuf[lane]);
        float part1 = gsum16_(redbuf[64 + lane]);
#pragma unroll
        for (int n = 0; n < N; ++n)
            v[n] = (n < 4) ? rdlane_(part0, 16 * n + 15)
                           : rdlane_(part1, 16 * (n - 4) + 15);
    }
}

// f16 pair dot-accumulate
__device__ __forceinline__ float dot2acc(uint32_t w, uint32_t h, float acc) {
#if defined(__has_builtin) && __has_builtin(__builtin_amdgcn_fdot2)
    return __builtin_amdgcn_fdot2(__builtin_bit_cast(half2_t, w),
                                  __builtin_bit_cast(half2_t, h), acc, false);
#else
    half2_t a = __builtin_bit_cast(half2_t, w);
    half2_t b = __builtin_bit_cast(half2_t, h);
    acc = fmaf((float)a[0], (float)b[0], acc);
    return fmaf((float)a[1], (float)b[1], acc);
#endif
}

// ---------- K1: transpose 2 ih weight matrices [768x256] -> [256x768] ----------
__global__ __launch_bounds__(256) void kt_transpose(
    const float* __restrict__ a0, const float* __restrict__ a1,
    float* __restrict__ o0, float* __restrict__ o1) {
    int idx = blockIdx.x * 256 + threadIdx.x;
    int m = idx / 196608, rem = idx % 196608;
    int j = rem >> 8, kk = rem & 255;
    const float* in = (m == 0) ? a0 : a1;
    float* outp     = (m == 0) ? o0 : o1;
    outp[kk * 768 + j] = in[j * 256 + kk];
}

// ---------- prep1: pack ALL h-side weights (W_hr,W_hz,W_hh_) f16 fragments ----
// QUARTER layout, 1024-thread scan: thread t: lane=t&63, wave=t>>6,
//   p = wave*16 + (lane&15), ph = lane>>4 (i-quarter, 64 wide).
// Register m in [0,96): m<64 -> stage1: g=m>>5 (0=r row p, 1=z row 512+p),
//   mi=m&31, i=64*ph+2*mi.  m>=64 -> stage2: row 256+p, mi=m-64, i=64*ph+2*mi.
// Stored for uint4-coalesced loads: u32 index e = (m>>2)*4096 + t*4 + (m&3).
__global__ __launch_bounds__(256) void kt_prep1(
    const float* __restrict__ whh0, const float* __restrict__ whh1,
    uint32_t* __restrict__ p0, uint32_t* __restrict__ p1) {
    int idx = blockIdx.x * 256 + threadIdx.x;  // 196608 total
    int l = idx / 98304, e = idx % 98304;
    int r4 = e >> 12, rem = e & 4095;
    int t = rem >> 2, m = r4 * 4 + (rem & 3);
    int lane = t & 63, wave = t >> 6;
    int p = wave * 16 + (lane & 15), ph = lane >> 4;
    int row, i;
    if (m < 64) {
        int g = m >> 5, mi = m & 31;
        row = g ? (512 + p) : p;
        i = 64 * ph + 2 * mi;
    } else {
        int mi = m - 64;
        row = 256 + p;
        i = 64 * ph + 2 * mi;
    }
    const float* w = l ? whh1 : whh0;
    half2_t hv;
    hv[0] = (half_t)w[row * 256 + i];
    hv[1] = (half_t)w[row * 256 + i + 1];
    (l ? p1 : p0)[e] = __builtin_bit_cast(uint32_t, hv);
}

// ---------- init / final ----------
__global__ __launch_bounds__(256) void kt_init(
    const float* __restrict__ h0, float* __restrict__ hcar) {
    int i = blockIdx.x * 256 + threadIdx.x;
    hcar[i] = h0[i];
}
__global__ __launch_bounds__(256) void kt_final(
    const float* __restrict__ hcar, float* __restrict__ dst) {
    int i = blockIdx.x * 256 + threadIdx.x;
    dst[i] = hcar[i];
}

// ---------- rowscale / gemm / mscale ----------
__global__ __launch_bounds__(256) void kt_rowscale(
    const float* __restrict__ src, long long strideB,
    float* __restrict__ s_arr, float* __restrict__ ax_arr,
    const float* __restrict__ kptr, int mode) {
    int lane = threadIdx.x & 63;
    int r = blockIdx.x * 4 + (threadIdx.x >> 6);
    float k = kptr[0], sk = sqrtf(-k), rsk = frcp_(sk);
    size_t off = (size_t)(r >> 6) * strideB + (size_t)(r & 63) * 256 + lane * 4;
    float4 v = *(const float4*)&src[off];
    float n2 = wave_sum(v.x * v.x + v.y * v.y + v.z * v.z + v.w * v.w);
    float n = sqrtf(n2);
    float s, xn;
    if (mode == 0) {
        float nrm = fmaxf(n, MINN);
        float tk = tan_k_(nrm, sk, rsk);
        s = tk * frcp_(nrm);
        xn = fmaxf(tk * (n * frcp_(nrm)), MINN);
    } else {
        s = 1.f;
        xn = fmaxf(n, MINN);
    }
    float ax = artan_k_(xn, sk, rsk) * frcp_(xn);
    if (lane == 0) { s_arr[r] = s; ax_arr[r] = ax; }
}

__global__ __launch_bounds__(256) void kt_gemm(
    const float* __restrict__ A, long long strideB,
    const float* __restrict__ s_arr,
    const float* __restrict__ Bt, float* __restrict__ C) {
    __shared__ float As[16][68];
    __shared__ float Bs[16][68];
    __shared__ float sS[64];
    int tid = threadIdx.x;
    int row0 = blockIdx.y * 64, col0 = blockIdx.x * 64;
    if (tid < 64) sS[tid] = s_arr[row0 + tid];
    int ty = tid >> 4, tx = tid & 15;
    int ra = tid >> 2, kq = tid & 3;
    int kb = tid >> 4, cq = tid & 15;
    float acc[4][4] = {};
    __syncthreads();
#pragma unroll 1
    for (int kt = 0; kt < 16; ++kt) {
        int k0 = kt * 16;
        int rc = row0 + ra;
        size_t aoff = (size_t)(rc >> 6) * strideB + (size_t)(rc & 63) * 256 + k0 + kq * 4;
        float4 av = *(const float4*)&A[aoff];
        float sc = sS[ra];
        float4 bv = *(const float4*)&Bt[(size_t)(k0 + kb) * 768 + col0 + cq * 4];
        As[kq * 4 + 0][ra] = av.x * sc;
        As[kq * 4 + 1][ra] = av.y * sc;
        As[kq * 4 + 2][ra] = av.z * sc;
        As[kq * 4 + 3][ra] = av.w * sc;
        *(float4*)&Bs[kb][cq * 4] = bv;
        __syncthreads();
#pragma unroll
        for (int kk = 0; kk < 16; ++kk) {
            float4 a4 = *(const float4*)&As[kk][ty * 4];
            float4 b4 = *(const float4*)&Bs[kk][tx * 4];
            float aa[4] = {a4.x, a4.y, a4.z, a4.w};
            float bb[4] = {b4.x, b4.y, b4.z, b4.w};
#pragma unroll
            for (int i = 0; i < 4; ++i)
#pragma unroll
                for (int j = 0; j < 4; ++j)
                    acc[i][j] = fmaf(aa[i], bb[j], acc[i][j]);
        }
        __syncthreads();
    }
#pragma unroll
    for (int i = 0; i < 4; ++i) {
        size_t row = (size_t)row0 + ty * 4 + i;
        *(float4*)&C[row * 768 + col0 + tx * 4] =
            make_float4(acc[i][0], acc[i][1], acc[i][2], acc[i][3]);
    }
}

// scales mx in place, stores ||Ux|| and (Ux . bias) per (row,gate)
__global__ __launch_bounds__(256) void kt_mscale(
    float* __restrict__ mx, const float* __restrict__ ax_arr,
    float* __restrict__ uxn, float* __restrict__ uxb,
    const float* __restrict__ bias, const float* __restrict__ kptr) {
    int lane = threadIdx.x & 63;
    int p = blockIdx.x * 4 + (threadIdx.x >> 6);
    int r = p / 3;
    int g = p - r * 3;
    float k = kptr[0], sk = sqrtf(-k), rsk = frcp_(sk);
    float* ptr = mx + (size_t)r * 768 + g * 256 + lane * 4;
    float4 v = *(const float4*)ptr;
    float4 b4 = *(const float4*)&bias[g * 256 + lane * 4];
    float n2 = wave_sum(v.x * v.x + v.y * v.y + v.z * v.z + v.w * v.w);
    float vb = wave_sum(v.x * b4.x + v.y * b4.y + v.z * b4.z + v.w * b4.w);
    float nt = sqrtf(n2);
    float mxn = fmaxf(nt, MINN);
    float arg = mxn * ax_arr[r];
    float tk = tan_k_(arg, sk, rsk);
    float f = tk * frcp_(mxn);
    v.x *= f; v.y *= f; v.z *= f; v.w *= f;
    *(float4*)ptr = v;
    if (lane == 0) { uxn[p] = tk * (nt * frcp_(mxn)); uxb[p] = f * vb; }
}

// ---------- K6: all-register-weight scan, dual-role, quarter layout ----------
// 1024 threads, 16 waves. Thread: lane=tid&63, wave=tid>>6;
//   p = wave*16 + (lane&15) in [0,256), ph = lane>>4 in {0..3}.
// Quarter partials combine via shfl_xor(16)+shfl_xor(32) (4 lanes share p).
// Block sums duplicated 4x per p -> scale by 0.25 after reduce.
__global__ __launch_bounds__(1024, 1) void kt_scan2(
    const float* __restrict__ Ux_0, const float* __restrict__ uxn_0,
    const float* __restrict__ uxb_0, const uint32_t* __restrict__ w1pk_0,
    const float* __restrict__ bias_0, float* __restrict__ hcar_0,
    float* __restrict__ out_0, long long sb_0, long long st_0,
    const float* __restrict__ Ux_1, const float* __restrict__ uxn_1,
    const float* __restrict__ uxb_1, const uint32_t* __restrict__ w1pk_1,
    const float* __restrict__ bias_1, float* __restrict__ hcar_1,
    float* __restrict__ out_1, long long sb_1, long long st_1,
    const float* __restrict__ kptr, int Tc, int nrole0) {
    __shared__ uint32_t hy2S[128];     // hy as 128 half2
    __shared__ uint32_t rh2S[128];     // wx (unscaled rh) as 128 half2
    __shared__ float redbuf[2][128];   // double-buffered reduce scratch

    const int tid = threadIdx.x;
    const int role = (blockIdx.x >= nrole0) ? 1 : 0;
    const int bb = role ? (int)blockIdx.x - nrole0 : (int)blockIdx.x;

    const float* Ux      = role ? Ux_1 : Ux_0;
    const float* uxn     = role ? uxn_1 : uxn_0;
    const float* uxb     = role ? uxb_1 : uxb_0;
    const uint32_t* w1pk = role ? w1pk_1 : w1pk_0;
    const float* bias    = role ? bias_1 : bias_0;
    float* hcar          = role ? hcar_1 : hcar_0;
    float* outbase       = role ? out_1 : out_0;
    const long long stride_b = role ? sb_1 : sb_0;
    const long long stride_t = role ? st_1 : st_0;

    const int lane = tid & 63, wave = tid >> 6;
    const int p = wave * 16 + (lane & 15);
    const int ph = lane >> 4;
    const float k = kptr[0], sk = sqrtf(-k), rsk = frcp_(sk);

    // ALL h-side weights -> registers (96 u32 = 192 f16 per thread)
    uint32_t w1[96];
    {
        const uint4* wp = (const uint4*)w1pk;  // [24][1024] uint4
#pragma unroll
        for (int r4 = 0; r4 < 24; ++r4) {
            uint4 v = wp[r4 * 1024 + tid];
            w1[4 * r4 + 0] = v.x; w1[4 * r4 + 1] = v.y;
            w1[4 * r4 + 2] = v.z; w1[4 * r4 + 3] = v.w;
        }
    }

    const float br = bias[p], bh = bias[256 + p], bz = bias[512 + p];
    float h = hcar[bb * 256 + p];
    __syncthreads();  // clean redbuf ordering before first bred
    float v4[4] = {br * br, bh * bh, bz * bz, h * h};
    bredX<4>(v4, redbuf[0], tid);
    const float bn2r = 0.25f * v4[0], bn2h = 0.25f * v4[1], bn2z = 0.25f * v4[2];
    float S_h2 = 0.25f * v4[3];

    float* myout = outbase + (size_t)bb * stride_b;
    const float* uxpb = Ux + (size_t)bb * Tc * 768;
    const float* unpb = uxn + (size_t)bb * Tc * 3;
    const float* ubpb = uxb + (size_t)bb * Tc * 3;

    // prefetch step 0
    float puxr = uxpb[p], puxh = uxpb[256 + p], puxz = uxpb[512 + p];
    float punr = unpb[0], punh = unpb[1], punz = unpb[2];
    float pubr = ubpb[0], pubh = ubpb[1], pubz = ubpb[2];

    for (int t = 0; t < Tc; ++t) {
        const float uxr = puxr, uxh = puxh, uxz = puxz;
        const float unr = punr, unh = punh, unz = punz;
        const float S_ubr = pubr, S_ubh = pubh, S_ubz = pubz;

        // ---- expmap0(h): scalars from carried S_h2 ----
        float hn = sqrtf(S_h2);
        float nrm = fmaxf(hn, MINN);
        float tk0 = tan_k_(nrm, sk, rsk);
        float chy = tk0 * frcp_(nrm);
        float hy = chy * h;
        float Shy2 = chy * chy * S_h2;
        float xnh = fmaxf(tk0 * (hn * frcp_(nrm)), MINN);
        float axh = artan_k_(xnh, sk, rsk) * frcp_(xnh);
        if (lane < 16) ((half_t*)hy2S)[p] = (half_t)hy;
        __syncthreads();  // B1: hy ready

        // prefetch next step (hidden under matvec + reductions)
        if (t + 1 < Tc) {
            const float* uxp2 = uxpb + (size_t)(t + 1) * 768;
            puxr = uxp2[p]; puxh = uxp2[256 + p]; puxz = uxp2[512 + p];
            const float* unp2 = unpb + (size_t)(t + 1) * 3;
            punr = unp2[0]; punh = unp2[1]; punz = unp2[2];
            const float* ubp2 = ubpb + (size_t)(t + 1) * 3;
            pubr = ubp2[0]; pubh = ubp2[1]; pubz = ubp2[2];
        }

        // ---- stage-1 matvec (r,z), quarter-split, 2-deep accumulators ----
        float pr0 = 0.f, pr1 = 0.f, pz0 = 0.f, pz1 = 0.f;
        {
            const uint4* hp = (const uint4*)hy2S + 8 * ph;
            uint4 hvv[8];
#pragma unroll
            for (int u = 0; u < 8; ++u) hvv[u] = hp[u];
#pragma unroll
            for (int u = 0; u < 8; ++u) {
                uint32_t a0 = hvv[u].x, a1 = hvv[u].y, a2 = hvv[u].z, a3 = hvv[u].w;
                if (u & 1) {
                    pr1 = dot2acc(w1[4 * u + 0], a0, pr1);
                    pr1 = dot2acc(w1[4 * u + 1], a1, pr1);
                    pr1 = dot2acc(w1[4 * u + 2], a2, pr1);
                    pr1 = dot2acc(w1[4 * u + 3], a3, pr1);
                    pz1 = dot2acc(w1[32 + 4 * u + 0], a0, pz1);
                    pz1 = dot2acc(w1[32 + 4 * u + 1], a1, pz1);
                    pz1 = dot2acc(w1[32 + 4 * u + 2], a2, pz1);
                    pz1 = dot2acc(w1[32 + 4 * u + 3], a3, pz1);
                } else {
                    pr0 = dot2acc(w1[4 * u + 0], a0, pr0);
                    pr0 = dot2acc(w1[4 * u + 1], a1, pr0);
                    pr0 = dot2acc(w1[4 * u + 2], a2, pr0);
                    pr0 = dot2acc(w1[4 * u + 3], a3, pr0);
                    pz0 = dot2acc(w1[32 + 4 * u + 0], a0, pz0);
                    pz0 = dot2acc(w1[32 + 4 * u + 1], a1, pz0);
                    pz0 = dot2acc(w1[32 + 4 * u + 2], a2, pz0);
                    pz0 = dot2acc(w1[32 + 4 * u + 3], a3, pz0);
                }
            }
        }
        float pr = pr0 + pr1, pz = pz0 + pz1;
        pr += __shfl_xor(pr, 16, 64); pr += __shfl_xor(pr, 32, 64);
        pz += __shfl_xor(pz, 16, 64); pz += __shfl_xor(pz, 32, 64);
        const float mr = pr, mz = pz;

        float vr[8] = {mr * mr, mz * mz, mr * uxr, mz * uxz,
                       mr * br, mz * bz, h * uxh, h * bh};
        bredX<8>(vr, redbuf[0], tid);
        const float S_mr2 = 0.25f * vr[0], S_mz2 = 0.25f * vr[1];
        const float S_mru = 0.25f * vr[2], S_mzu = 0.25f * vr[3];
        const float S_mrb = 0.25f * vr[4], S_mzb = 0.25f * vr[5];
        const float S_huxh = 0.25f * vr[6], S_hbh = 0.25f * vr[7];

        float r_t, z_t;
        {   // --- r gate ---
            float mxn = fmaxf(sqrtf(S_mr2), MINN);
            float tk = tan_k_(mxn * axh, sk, rsk);
            float f = tk * frcp_(mxn);
            float x2 = f * f * S_mr2, y2 = unr * unr, xy = f * S_mru;
            float a = 1.f - 2.f * k * xy - k * y2;
            float bq = 1.f + k * x2;
            float rd = frcp_(fmaxf(1.f - 2.f * k * xy + k * k * x2 * y2, MINN));
            float c1 = (a * f * mr + bq * uxr) * rd;
            float Sc12 = (a * a * x2 + 2.f * a * bq * xy + bq * bq * y2) * (rd * rd);
            float Sc1b = (a * f * S_mrb + bq * S_ubr) * rd;
            float g = 1.f - 2.f * k * Sc1b - k * bn2r;
            float dl = 1.f + k * Sc12;
            float re = frcp_(fmaxf(1.f - 2.f * k * Sc1b + k * k * Sc12 * bn2r, MINN));
            float c2 = (g * c1 + dl * br) * re;
            float Sc22 = (g * g * Sc12 + 2.f * g * dl * Sc1b + dl * dl * bn2r) * (re * re);
            float yn = fmaxf(sqrtf(Sc22), MINN);
            float lr = artan_k_(yn, sk, rsk) * frcp_(yn) * c2;
            r_t = sigm_(lr);
        }
        {   // --- z gate ---
            float mxn = fmaxf(sqrtf(S_mz2), MINN);
            float tk = tan_k_(mxn * axh, sk, rsk);
            float f = tk * frcp_(mxn);
            float x2 = f * f * S_mz2, y2 = unz * unz, xy = f * S_mzu;
            float a = 1.f - 2.f * k * xy - k * y2;
            float bq = 1.f + k * x2;
            float rd = frcp_(fmaxf(1.f - 2.f * k * xy + k * k * x2 * y2, MINN));
            float c1 = (a * f * mz + bq * uxz) * rd;
            float Sc12 = (a * a * x2 + 2.f * a * bq * xy + bq * bq * y2) * (rd * rd);
            float Sc1b = (a * f * S_mzb + bq * S_ubz) * rd;
            float g = 1.f - 2.f * k * Sc1b - k * bn2z;
            float dl = 1.f + k * Sc12;
            float re = frcp_(fmaxf(1.f - 2.f * k * Sc1b + k * k * Sc12 * bn2z, MINN));
            float c2 = (g * c1 + dl * bz) * re;
            float Sc22 = (g * g * Sc12 + 2.f * g * dl * Sc1b + dl * dl * bn2z) * (re * re);
            float yn = fmaxf(sqrtf(Sc22), MINN);
            float lz = artan_k_(yn, sk, rsk) * frcp_(yn) * c2;
            z_t = sigm_(lz);
        }

        // ---- rh: publish UNSCALED wx; merge S_wx2 reduction into same barrier ----
        float wx = r_t * hy;
        if (lane < 16) ((half_t*)rh2S)[p] = (half_t)wx;
        {
            float s1v = wsum63_(wx * wx);
            if (lane == 63) redbuf[1][wave] = s1v;
        }
        __syncthreads();  // B_B: rh/wx ready + partials ready

        float part1 = gsum16_(redbuf[1][lane & 15]);
        const float S_wx2 = 0.25f * rdlane_(part1, 15);
        float wxt = sqrtf(S_wx2);
        float wxn = fmaxf(wxt, MINN);
        float tkw = tan_k_(wxn * axh, sk, rsk);
        float fw = tkw * frcp_(wxn);      // rh = fw * wx (block scalar)
        float rhn = tkw * (wxt * frcp_(wxn));

        // ---- stage-2 matvec (h gate), quarter-split, register weights ----
        float q0 = 0.f, q1 = 0.f;
        {
            const uint4* rp = (const uint4*)rh2S + 8 * ph;
            uint4 rvv[8];
#pragma unroll
            for (int u = 0; u < 8; ++u) rvv[u] = rp[u];
#pragma unroll
            for (int u = 0; u < 8; ++u) {
                uint32_t a0 = rvv[u].x, a1 = rvv[u].y, a2 = rvv[u].z, a3 = rvv[u].w;
                if (u & 1) {
                    q1 = dot2acc(w1[64 + 4 * u + 0], a0, q1);
                    q1 = dot2acc(w1[64 + 4 * u + 1], a1, q1);
                    q1 = dot2acc(w1[64 + 4 * u + 2], a2, q1);
                    q1 = dot2acc(w1[64 + 4 * u + 3], a3, q1);
                } else {
                    q0 = dot2acc(w1[64 + 4 * u + 0], a0, q0);
                    q0 = dot2acc(w1[64 + 4 * u + 1], a1, q0);
                    q0 = dot2acc(w1[64 + 4 * u + 2], a2, q0);
                    q0 = dot2acc(w1[64 + 4 * u + 3], a3, q0);
                }
            }
        }
        float qq = q0 + q1;
        qq += __shfl_xor(qq, 16, 64); qq += __shfl_xor(qq, 32, 64);
        const float mh = fw * qq;

        float v4b[4] = {mh * mh, mh * uxh, mh * bh, hy * mh};
        bredX<4>(v4b, redbuf[0], tid);
        const float S_mh2 = 0.25f * v4b[0], S_mhu = 0.25f * v4b[1];
        const float S_mhb = 0.25f * v4b[2], S_hymh = 0.25f * v4b[3];

        float wz, Sdelta2;
        {
            float xnrh = fmaxf(rhn, MINN);
            float axrh = artan_k_(xnrh, sk, rsk) * frcp_(xnrh);
            float mxn = fmaxf(sqrtf(S_mh2), MINN);
            float tk = tan_k_(mxn * axrh, sk, rsk);
            float f = tk * frcp_(mxn);
            float x2 = f * f * S_mh2, y2 = unh * unh, xy = f * S_mhu;
            float a = 1.f - 2.f * k * xy - k * y2;
            float bq = 1.f + k * x2;
            float rd = frcp_(fmaxf(1.f - 2.f * k * xy + k * k * x2 * y2, MINN));
            float c1 = (a * f * mh + bq * uxh) * rd;
            float Sc12 = (a * a * x2 + 2.f * a * bq * xy + bq * bq * y2) * (rd * rd);
            float Sc1b = (a * f * S_mhb + bq * S_ubh) * rd;
            float S_hyc1 = (a * f * S_hymh + bq * chy * S_huxh) * rd;
            float g = 1.f - 2.f * k * Sc1b - k * bn2h;
            float dl = 1.f + k * Sc12;
            float re = frcp_(fmaxf(1.f - 2.f * k * Sc1b + k * k * Sc12 * bn2h, MINN));
            float htl = (g * c1 + dl * bh) * re;
            float Shtl2 = (g * g * Sc12 + 2.f * g * dl * Sc1b + dl * dl * bn2h) * (re * re);
            float S_hyhtl = (g * S_hyc1 + dl * chy * S_hbh) * re;
            // delta = mobius_add(-hy, htl): xy_d = -S_hyhtl
            float ad = 1.f + 2.f * k * S_hyhtl - k * Shtl2;
            float bd = 1.f + k * Shy2;
            float rdd = frcp_(fmaxf(1.f + 2.f * k * S_hyhtl + k * k * Shy2 * Shtl2, MINN));
            float delta = (ad * (-hy) + bd * htl) * rdd;
            Sdelta2 = (ad * ad * Shy2 - 2.f * ad * bd * S_hyhtl + bd * bd * Shtl2) * (rdd * rdd);
            wz = z_t * delta;
        }
        float v2[2] = {wz * wz, hy * wz};
        bredX<2>(v2, redbuf[1], tid);
        const float S_wz2 = 0.25f * v2[0], S_hywz = 0.25f * v2[1];

        {
            float dnc = fmaxf(sqrtf(Sdelta2), MINN);
            float axd = artan_k_(dnc, sk, rsk) * frcp_(dnc);
            float wzt = sqrtf(S_wz2);
            float wznc = fmaxf(wzt, MINN);
            float tkzd = tan_k_(wznc * axd, sk, rsk);
            float fz = tkzd * frcp_(wznc);
            float zd = fz * wz;
            float zdn2 = fz * fz * S_wz2;
            float S_hyzd = fz * S_hywz;
            float an = 1.f - 2.f * k * S_hyzd - k * zdn2;
            float bn_ = 1.f + k * Shy2;
            float rdn = frcp_(fmaxf(1.f - 2.f * k * S_hyzd + k * k * Shy2 * zdn2, MINN));
            float hnew = (an * hy + bn_ * zd) * rdn;
            float Shnew2 = (an * an * Shy2 + 2.f * an * bn_ * S_hyzd + bn_ * bn_ * zdn2) * (rdn * rdn);
            float yn = fmaxf(sqrtf(Shnew2), MINN);
            float ayn = artan_k_(yn, sk, rsk) * frcp_(yn);
            float outv = ayn * hnew;
            if (lane < 16) myout[(size_t)t * stride_t + p] = outv;
            h = outv;
            S_h2 = ayn * ayn * Shnew2;  // carried, no reduction needed
        }
    }
    if (lane < 16) hcar[bb * 256 + p] = h;
}

// ---------- host launcher ----------
extern "C" void kernel_launch(void* const* d_in, const int* in_sizes, int n_in,
                              void* d_out, int out_size, void* d_ws, size_t ws_size,
                              hipStream_t stream) {
    const float* x    = (const float*)d_in[0];
    const float* kptr = (const float*)d_in[1];
    const float* h0   = (const float*)d_in[2];
    const float* wih0 = (const float*)d_in[3];
    const float* whh0 = (const float*)d_in[4];
    const float* b0   = (const float*)d_in[5];
    const float* wih1 = (const float*)d_in[6];
    const float* whh1 = (const float*)d_in[7];
    const float* b1   = (const float*)d_in[8];
    float* out = (float*)d_out;
    float* ws  = (float*)d_ws;

    const int B = 64, T = 1024, H = 256;
    const int CT = 64, NC = 16;
    const int RC = B * CT;  // 4096

    float* wt_ih0 = ws;
    float* wt_ih1 = wt_ih0 + 196608;
    uint32_t* w1pk0 = (uint32_t*)(wt_ih1 + 196608);  // 98304 u32 each
    uint32_t* w1pk1 = w1pk0 + 98304;
    float* hcar  = (float*)(w1pk1 + 98304);
    float* s0    = hcar + 32768;
    float* ax0   = s0 + RC;
    float* s1    = ax0 + RC;
    float* ax1   = s1 + RC;
    float* uxn0  = ax1 + RC;
    float* uxn1  = uxn0 + 3 * RC;
    float* uxb0  = uxn1 + 3 * RC;
    float* uxb1  = uxb0 + 3 * RC;
    float* out0c = uxb1 + 3 * RC;
    float* mx0   = out0c + (size_t)RC * H;
    float* mx1   = mx0 + (size_t)RC * 768;

    float* hcar0 = hcar;
    float* hcar1 = hcar + (size_t)B * H;

    dim3 blk(256);
    kt_transpose<<<dim3(1536), blk, 0, stream>>>(wih0, wih1, wt_ih0, wt_ih1);
    kt_prep1<<<dim3(768), blk, 0, stream>>>(whh0, whh1, w1pk0, w1pk1);
    kt_init<<<dim3(128), blk, 0, stream>>>(h0, hcar);

    const long long sbx = (long long)T * 256;
    const long long sbc = (long long)CT * 256;

    // ---- prologue: layer 0, chunk 0 ----
    {
        const float* xc = x;
        kt_rowscale<<<dim3(RC / 4), blk, 0, stream>>>(xc, sbx, s0, ax0, kptr, 0);
        kt_gemm<<<dim3(12, RC / 64), blk, 0, stream>>>(xc, sbx, s0, wt_ih0, mx0);
        kt_mscale<<<dim3(RC * 3 / 4), blk, 0, stream>>>(mx0, ax0, uxn0, uxb0, b0, kptr);
        kt_scan2<<<dim3(B), dim3(1024), 0, stream>>>(
            mx0, uxn0, uxb0, w1pk0, b0, hcar0, out0c, sbc, 256LL,
            mx0, uxn0, uxb0, w1pk0, b0, hcar0, out0c, sbc, 256LL,
            kptr, CT, B);
    }
    // ---- steady state: dual scans (L0 chunk c || L1 chunk c-1) ----
    for (int c = 1; c < NC; ++c) {
        const float* xc = x + (size_t)c * CT * 256;
        kt_rowscale<<<dim3(RC / 4), blk, 0, stream>>>(xc, sbx, s0, ax0, kptr, 0);
        kt_gemm<<<dim3(12, RC / 64), blk, 0, stream>>>(xc, sbx, s0, wt_ih0, mx0);
        kt_mscale<<<dim3(RC * 3 / 4), blk, 0, stream>>>(mx0, ax0, uxn0, uxb0, b0, kptr);
        kt_rowscale<<<dim3(RC / 4), blk, 0, stream>>>(out0c, sbc, s1, ax1, kptr, 1);
        kt_gemm<<<dim3(12, RC / 64), blk, 0, stream>>>(out0c, sbc, s1, wt_ih1, mx1);
        kt_mscale<<<dim3(RC * 3 / 4), blk, 0, stream>>>(mx1, ax1, uxn1, uxb1, b1, kptr);
        kt_scan2<<<dim3(2 * B), dim3(1024), 0, stream>>>(
            mx0, uxn0, uxb0, w1pk0, b0, hcar0, out0c, sbc, 256LL,
            mx1, uxn1, uxb1, w1pk1, b1, hcar1,
            out + (size_t)(c - 1) * CT * B * H, 256LL, (long long)B * H,
            kptr, CT, B);
    }
    // ---- epilogue: layer 1, chunk NC-1 ----
    {
        kt_rowscale<<<dim3(RC / 4), blk, 0, stream>>>(out0c, sbc, s1, ax1, kptr, 1);
        kt_gemm<<<dim3(12, RC / 64), blk, 0, stream>>>(out0c, sbc, s1, wt_ih1, mx1);
        kt_mscale<<<dim3(RC * 3 / 4), blk, 0, stream>>>(mx1, ax1, uxn1, uxb1, b1, kptr);
        kt_scan2<<<dim3(B), dim3(1024), 0, stream>>>(
            mx1, uxn1, uxb1, w1pk1, b1, hcar1,
            out + (size_t)(NC - 1) * CT * B * H, 256LL, (long long)B * H,
            mx1, uxn1, uxb1, w1pk1, b1, hcar1,
            out + (size_t)(NC - 1) * CT * B * H, 256LL, (long long)B * H,
            kptr, CT, B);
    }
    kt_final<<<dim3(128), blk, 0, stream>>>(hcar, out + (size_t)T * B * H);
}

// Round 9
// 8912.044 us; speedup vs baseline: 1.4959x; 1.4959x over previous
//
#include <hip/hip_runtime.h>
#include <cstdint>
#include <cstddef>

#define MINN 1e-15f
#define EPSA 1e-7f
#define C_L2E 1.44269504088896341f
#define C_LN2 0.69314718055994531f

typedef _Float16 half_t;
typedef _Float16 half2_t __attribute__((ext_vector_type(2)));

#if defined(__has_builtin)
#if __has_builtin(__builtin_amdgcn_update_dpp) && __has_builtin(__builtin_amdgcn_readlane)
#define USE_DPP 1
#endif
#endif

// ---------- fast-math helpers (native, ~1 ulp) ----------
__device__ __forceinline__ float fexp2_(float x) {
#if defined(__has_builtin) && __has_builtin(__builtin_amdgcn_exp2f)
    return __builtin_amdgcn_exp2f(x);
#else
    return exp2f(x);
#endif
}
__device__ __forceinline__ float flog2_(float x) {
#if defined(__has_builtin) && __has_builtin(__builtin_amdgcn_logf)
    return __builtin_amdgcn_logf(x);
#else
    return log2f(x);
#endif
}
__device__ __forceinline__ float frcp_(float x) {
#if defined(__has_builtin) && __has_builtin(__builtin_amdgcn_rcpf)
    return __builtin_amdgcn_rcpf(x);
#else
    return 1.f / x;
#endif
}
__device__ __forceinline__ float tan_k_(float u, float sk, float rsk) {
    float a = fminf(fmaxf(sk * u, -15.f), 15.f);
    float t = fexp2_(a * (2.f * C_L2E));
    return (1.f - 2.f * frcp_(t + 1.f)) * rsk;
}
__device__ __forceinline__ float artan_k_(float u, float sk, float rsk) {
    float a = fminf(fmaxf(sk * u, -1.f + EPSA), 1.f - EPSA);
    return flog2_((1.f + a) * frcp_(1.f - a)) * (0.5f * C_LN2) * rsk;
}
__device__ __forceinline__ float sigm_(float x) {
    return frcp_(1.f + fexp2_(-x * C_L2E));
}
__device__ __forceinline__ float wave_sum(float v) {
#pragma unroll
    for (int off = 32; off; off >>= 1) v += __shfl_xor(v, off, 64);
    return v;
}

// ---------- DPP reduction primitives (VALU pipe, not DS) ----------
#ifdef USE_DPP
template <int CTRL, int RM, int BM>
__device__ __forceinline__ float dppmov_(float x) {
    return __builtin_bit_cast(float,
        __builtin_amdgcn_update_dpp(0, __builtin_bit_cast(int, x), CTRL, RM, BM, false));
}
#endif
// full 64-lane sum; result valid in lane 63 (fallback: all lanes)
__device__ __forceinline__ float wsum63_(float x) {
#ifdef USE_DPP
    x += dppmov_<0x111, 0xf, 0xf>(x);  // row_shr:1
    x += dppmov_<0x112, 0xf, 0xf>(x);  // row_shr:2
    x += dppmov_<0x114, 0xf, 0xe>(x);  // row_shr:4
    x += dppmov_<0x118, 0xf, 0xc>(x);  // row_shr:8
    x += dppmov_<0x142, 0xa, 0xf>(x);  // row_bcast:15
    x += dppmov_<0x143, 0xc, 0xf>(x);  // row_bcast:31 -> lane63 = total
    return x;
#else
    return wave_sum(x);
#endif
}
// 16-lane row sum; result valid in lane 16k+15 (fallback: all lanes)
__device__ __forceinline__ float gsum16_(float x) {
#ifdef USE_DPP
    x += dppmov_<0x111, 0xf, 0xf>(x);
    x += dppmov_<0x112, 0xf, 0xf>(x);
    x += dppmov_<0x114, 0xf, 0xe>(x);
    x += dppmov_<0x118, 0xf, 0xc>(x);
    return x;
#else
    x += __shfl_xor(x, 1, 64);
    x += __shfl_xor(x, 2, 64);
    x += __shfl_xor(x, 4, 64);
    x += __shfl_xor(x, 8, 64);
    return x;
#endif
}
__device__ __forceinline__ float rdlane_(float x, int l) {
#ifdef USE_DPP
    return __builtin_bit_cast(float,
        __builtin_amdgcn_readlane(__builtin_bit_cast(int, x), l));
#else
    return __shfl(x, l, 64);
#endif
}
// block(1024,16-wave) reduce of N values (N in {2,4,8}); ONE internal barrier.
// redbuf needs 16*N floats. Caller alternates buffers between consecutive uses.
template <int N>
__device__ __forceinline__ void bredX(float* v, float* redbuf, int tid) {
    const int lane = tid & 63, wave = tid >> 6;
#pragma unroll
    for (int n = 0; n < N; ++n) {
        float s = wsum63_(v[n]);
        if (lane == 63) redbuf[n * 16 + wave] = s;
    }
    __syncthreads();
    if (N <= 4) {
        float part = gsum16_(redbuf[lane & (16 * N - 1)]);
#pragma unroll
        for (int n = 0; n < N; ++n) v[n] = rdlane_(part, 16 * n + 15);
    } else {
        float part0 = gsum16_(redbuf[lane]);
        float part1 = gsum16_(redbuf[64 + lane]);
#pragma unroll
        for (int n = 0; n < N; ++n)
            v[n] = (n < 4) ? rdlane_(part0, 16 * n + 15)
                           : rdlane_(part1, 16 * (n - 4) + 15);
    }
}

// f16 pair dot-accumulate
__device__ __forceinline__ float dot2acc(uint32_t w, uint32_t h, float acc) {
#if defined(__has_builtin) && __has_builtin(__builtin_amdgcn_fdot2)
    return __builtin_amdgcn_fdot2(__builtin_bit_cast(half2_t, w),
                                  __builtin_bit_cast(half2_t, h), acc, false);
#else
    half2_t a = __builtin_bit_cast(half2_t, w);
    half2_t b = __builtin_bit_cast(half2_t, h);
    acc = fmaf((float)a[0], (float)b[0], acc);
    return fmaf((float)a[1], (float)b[1], acc);
#endif
}

// ---------- K1: transpose 2 ih weight matrices [768x256] -> [256x768] ----------
__global__ __launch_bounds__(256) void kt_transpose(
    const float* __restrict__ a0, const float* __restrict__ a1,
    float* __restrict__ o0, float* __restrict__ o1) {
    int idx = blockIdx.x * 256 + threadIdx.x;
    int m = idx / 196608, rem = idx % 196608;
    int j = rem >> 8, kk = rem & 255;
    const float* in = (m == 0) ? a0 : a1;
    float* outp     = (m == 0) ? o0 : o1;
    outp[kk * 768 + j] = in[j * 256 + kk];
}

// ---------- prep1: pack stage-1 (W_hr,W_hz) f16 per-thread fragments ----------
// QUARTER layout, 1024-thread scan: thread t: lane=t&63, wave=t>>6,
//   p = wave*16 + (lane&15), ph = lane>>4 (i-quarter, 64 wide).
// Register m in [0,64): g=m>>5 (0=r row p, 1=z row 512+p), mi=m&31,
//   i = 64*ph + 2*mi.
// Stored for uint4-coalesced loads: u32 index e = (m>>2)*4096 + t*4 + (m&3).
__global__ __launch_bounds__(256) void kt_prep1(
    const float* __restrict__ whh0, const float* __restrict__ whh1,
    uint32_t* __restrict__ p0, uint32_t* __restrict__ p1) {
    int idx = blockIdx.x * 256 + threadIdx.x;  // 131072 total
    int l = idx >> 16, e = idx & 65535;
    int r4 = e >> 12, rem = e & 4095;
    int t = rem >> 2, m = r4 * 4 + (rem & 3);
    int lane = t & 63, wave = t >> 6;
    int p = wave * 16 + (lane & 15), ph = lane >> 4;
    int g = m >> 5, mi = m & 31;
    int row = g ? (512 + p) : p;
    int i = 64 * ph + 2 * mi;
    const float* w = l ? whh1 : whh0;
    half2_t hv;
    hv[0] = (half_t)w[row * 256 + i];
    hv[1] = (half_t)w[row * 256 + i + 1];
    (l ? p1 : p0)[e] = __builtin_bit_cast(uint32_t, hv);
}

// ---------- prep2: pack stage-2 (W_hh_) f16 [i2][j] half2 ----------
__global__ __launch_bounds__(256) void kt_prep2(
    const float* __restrict__ whh0, const float* __restrict__ whh1,
    uint32_t* __restrict__ p0, uint32_t* __restrict__ p1) {
    int idx = blockIdx.x * 256 + threadIdx.x;  // 65536
    int l = idx >> 15, e = idx & 32767;
    int i2 = e >> 8, j = e & 255;
    const float* w = l ? whh1 : whh0;
    half2_t hv;
    hv[0] = (half_t)w[(256 + j) * 256 + 2 * i2];
    hv[1] = (half_t)w[(256 + j) * 256 + 2 * i2 + 1];
    (l ? p1 : p0)[e] = __builtin_bit_cast(uint32_t, hv);
}

// ---------- init / final ----------
__global__ __launch_bounds__(256) void kt_init(
    const float* __restrict__ h0, float* __restrict__ hcar) {
    int i = blockIdx.x * 256 + threadIdx.x;
    hcar[i] = h0[i];
}
__global__ __launch_bounds__(256) void kt_final(
    const float* __restrict__ hcar, float* __restrict__ dst) {
    int i = blockIdx.x * 256 + threadIdx.x;
    dst[i] = hcar[i];
}

// ---------- rowscale / gemm / mscale ----------
__global__ __launch_bounds__(256) void kt_rowscale(
    const float* __restrict__ src, long long strideB,
    float* __restrict__ s_arr, float* __restrict__ ax_arr,
    const float* __restrict__ kptr, int mode) {
    int lane = threadIdx.x & 63;
    int r = blockIdx.x * 4 + (threadIdx.x >> 6);
    float k = kptr[0], sk = sqrtf(-k), rsk = frcp_(sk);
    size_t off = (size_t)(r >> 6) * strideB + (size_t)(r & 63) * 256 + lane * 4;
    float4 v = *(const float4*)&src[off];
    float n2 = wave_sum(v.x * v.x + v.y * v.y + v.z * v.z + v.w * v.w);
    float n = sqrtf(n2);
    float s, xn;
    if (mode == 0) {
        float nrm = fmaxf(n, MINN);
        float tk = tan_k_(nrm, sk, rsk);
        s = tk * frcp_(nrm);
        xn = fmaxf(tk * (n * frcp_(nrm)), MINN);
    } else {
        s = 1.f;
        xn = fmaxf(n, MINN);
    }
    float ax = artan_k_(xn, sk, rsk) * frcp_(xn);
    if (lane == 0) { s_arr[r] = s; ax_arr[r] = ax; }
}

__global__ __launch_bounds__(256) void kt_gemm(
    const float* __restrict__ A, long long strideB,
    const float* __restrict__ s_arr,
    const float* __restrict__ Bt, float* __restrict__ C) {
    __shared__ float As[16][68];
    __shared__ float Bs[16][68];
    __shared__ float sS[64];
    int tid = threadIdx.x;
    int row0 = blockIdx.y * 64, col0 = blockIdx.x * 64;
    if (tid < 64) sS[tid] = s_arr[row0 + tid];
    int ty = tid >> 4, tx = tid & 15;
    int ra = tid >> 2, kq = tid & 3;
    int kb = tid >> 4, cq = tid & 15;
    float acc[4][4] = {};
    __syncthreads();
#pragma unroll 1
    for (int kt = 0; kt < 16; ++kt) {
        int k0 = kt * 16;
        int rc = row0 + ra;
        size_t aoff = (size_t)(rc >> 6) * strideB + (size_t)(rc & 63) * 256 + k0 + kq * 4;
        float4 av = *(const float4*)&A[aoff];
        float sc = sS[ra];
        float4 bv = *(const float4*)&Bt[(size_t)(k0 + kb) * 768 + col0 + cq * 4];
        As[kq * 4 + 0][ra] = av.x * sc;
        As[kq * 4 + 1][ra] = av.y * sc;
        As[kq * 4 + 2][ra] = av.z * sc;
        As[kq * 4 + 3][ra] = av.w * sc;
        *(float4*)&Bs[kb][cq * 4] = bv;
        __syncthreads();
#pragma unroll
        for (int kk = 0; kk < 16; ++kk) {
            float4 a4 = *(const float4*)&As[kk][ty * 4];
            float4 b4 = *(const float4*)&Bs[kk][tx * 4];
            float aa[4] = {a4.x, a4.y, a4.z, a4.w};
            float bb[4] = {b4.x, b4.y, b4.z, b4.w};
#pragma unroll
            for (int i = 0; i < 4; ++i)
#pragma unroll
                for (int j = 0; j < 4; ++j)
                    acc[i][j] = fmaf(aa[i], bb[j], acc[i][j]);
        }
        __syncthreads();
    }
#pragma unroll
    for (int i = 0; i < 4; ++i) {
        size_t row = (size_t)row0 + ty * 4 + i;
        *(float4*)&C[row * 768 + col0 + tx * 4] =
            make_float4(acc[i][0], acc[i][1], acc[i][2], acc[i][3]);
    }
}

// scales mx in place, stores ||Ux|| and (Ux . bias) per (row,gate)
__global__ __launch_bounds__(256) void kt_mscale(
    float* __restrict__ mx, const float* __restrict__ ax_arr,
    float* __restrict__ uxn, float* __restrict__ uxb,
    const float* __restrict__ bias, const float* __restrict__ kptr) {
    int lane = threadIdx.x & 63;
    int p = blockIdx.x * 4 + (threadIdx.x >> 6);
    int r = p / 3;
    int g = p - r * 3;
    float k = kptr[0], sk = sqrtf(-k), rsk = frcp_(sk);
    float* ptr = mx + (size_t)r * 768 + g * 256 + lane * 4;
    float4 v = *(const float4*)ptr;
    float4 b4 = *(const float4*)&bias[g * 256 + lane * 4];
    float n2 = wave_sum(v.x * v.x + v.y * v.y + v.z * v.z + v.w * v.w);
    float vb = wave_sum(v.x * b4.x + v.y * b4.y + v.z * b4.z + v.w * b4.w);
    float nt = sqrtf(n2);
    float mxn = fmaxf(nt, MINN);
    float arg = mxn * ax_arr[r];
    float tk = tan_k_(arg, sk, rsk);
    float f = tk * frcp_(mxn);
    v.x *= f; v.y *= f; v.z *= f; v.w *= f;
    *(float4*)ptr = v;
    if (lane == 0) { uxn[p] = tk * (nt * frcp_(mxn)); uxb[p] = f * vb; }
}

// ---------- K6: scan, dual-role, quarter layout, 16 waves ----------
// 1024 threads. Thread: lane=tid&63, wave=tid>>6;
//   p = wave*16 + (lane&15) in [0,256), ph = lane>>4 in {0..3}.
// Stage-1 weights: 64 u32/thread in registers. Stage-2 weights: LDS (f16).
// Quarter partials combine via shfl_xor(16)+shfl_xor(32).
// Block sums duplicated 4x per p -> scale by 0.25 after reduce.
__global__ __launch_bounds__(1024, 4) void kt_scan2(
    const float* __restrict__ Ux_0, const float* __restrict__ uxn_0,
    const float* __restrict__ uxb_0, const uint32_t* __restrict__ w1pk_0,
    const uint32_t* __restrict__ whh2g_0,
    const float* __restrict__ bias_0, float* __restrict__ hcar_0,
    float* __restrict__ out_0, long long sb_0, long long st_0,
    const float* __restrict__ Ux_1, const float* __restrict__ uxn_1,
    const float* __restrict__ uxb_1, const uint32_t* __restrict__ w1pk_1,
    const uint32_t* __restrict__ whh2g_1,
    const float* __restrict__ bias_1, float* __restrict__ hcar_1,
    float* __restrict__ out_1, long long sb_1, long long st_1,
    const float* __restrict__ kptr, int Tc, int nrole0) {
    __shared__ uint4 whhS[8192];       // 128 KiB: W_hh_ f16, [i2-quad][j]
    __shared__ uint32_t hy2S[128];     // hy as 128 half2
    __shared__ uint32_t rh2S[128];     // wx (unscaled rh) as 128 half2
    __shared__ float redbuf[2][128];   // double-buffered reduce scratch

    const int tid = threadIdx.x;
    const int role = (blockIdx.x >= nrole0) ? 1 : 0;
    const int bb = role ? (int)blockIdx.x - nrole0 : (int)blockIdx.x;

    const float* Ux      = role ? Ux_1 : Ux_0;
    const float* uxn     = role ? uxn_1 : uxn_0;
    const float* uxb     = role ? uxb_1 : uxb_0;
    const uint32_t* w1pk = role ? w1pk_1 : w1pk_0;
    const uint32_t* whh2g= role ? whh2g_1 : whh2g_0;
    const float* bias    = role ? bias_1 : bias_0;
    float* hcar          = role ? hcar_1 : hcar_0;
    float* outbase       = role ? out_1 : out_0;
    const long long stride_b = role ? sb_1 : sb_0;
    const long long stride_t = role ? st_1 : st_0;

    const int lane = tid & 63, wave = tid >> 6;
    const int p = wave * 16 + (lane & 15);
    const int ph = lane >> 4;
    const float k = kptr[0], sk = sqrtf(-k), rsk = frcp_(sk);

    // stage-2 weights -> LDS
    for (int idx = tid; idx < 32768; idx += 1024) {
        uint32_t v = whh2g[idx];
        int i2 = idx >> 8, col = idx & 255;
        ((uint32_t*)whhS)[((i2 >> 2) * 256 + col) * 4 + (i2 & 3)] = v;
    }
    // stage-1 weights -> registers (64 u32 = 128 f16 per thread)
    uint32_t w1[64];
    {
        const uint4* wp = (const uint4*)w1pk;  // [16][1024] uint4
#pragma unroll
        for (int r4 = 0; r4 < 16; ++r4) {
            uint4 v = wp[r4 * 1024 + tid];
            w1[4 * r4 + 0] = v.x; w1[4 * r4 + 1] = v.y;
            w1[4 * r4 + 2] = v.z; w1[4 * r4 + 3] = v.w;
        }
    }

    const float br = bias[p], bh = bias[256 + p], bz = bias[512 + p];
    float h = hcar[bb * 256 + p];
    __syncthreads();  // whhS ready; clean redbuf ordering
    float v4[4] = {br * br, bh * bh, bz * bz, h * h};
    bredX<4>(v4, redbuf[0], tid);
    const float bn2r = 0.25f * v4[0], bn2h = 0.25f * v4[1], bn2z = 0.25f * v4[2];
    float S_h2 = 0.25f * v4[3];

    float* myout = outbase + (size_t)bb * stride_b;
    const float* uxpb = Ux + (size_t)bb * Tc * 768;
    const float* unpb = uxn + (size_t)bb * Tc * 3;
    const float* ubpb = uxb + (size_t)bb * Tc * 3;

    for (int t = 0; t < Tc; ++t) {
        // ---- expmap0(h): scalars from carried S_h2 ----
        float hn = sqrtf(S_h2);
        float nrm = fmaxf(hn, MINN);
        float tk0 = tan_k_(nrm, sk, rsk);
        float chy = tk0 * frcp_(nrm);
        float hy = chy * h;
        float Shy2 = chy * chy * S_h2;
        float xnh = fmaxf(tk0 * (hn * frcp_(nrm)), MINN);
        float axh = artan_k_(xnh, sk, rsk) * frcp_(xnh);
        if (lane < 16) ((half_t*)hy2S)[p] = (half_t)hy;
        __syncthreads();  // B1: hy ready

        // current-step operand loads (consumed ~300cy later, after bred8)
        const float* uxp = uxpb + (size_t)t * 768;
        float uxr = uxp[p], uxh = uxp[256 + p], uxz = uxp[512 + p];
        const float* unp = unpb + (size_t)t * 3;
        float unr = unp[0], unh = unp[1], unz = unp[2];
        const float* ubp = ubpb + (size_t)t * 3;
        float S_ubr = ubp[0], S_ubh = ubp[1], S_ubz = ubp[2];

        // ---- stage-1 matvec (r,z), quarter-split ----
        float pr0 = 0.f, pr1 = 0.f, pz0 = 0.f, pz1 = 0.f;
        {
            const uint4* hp = (const uint4*)hy2S + 8 * ph;
#pragma unroll
            for (int u = 0; u < 8; ++u) {
                uint4 a = hp[u];
                if (u & 1) {
                    pr1 = dot2acc(w1[4 * u + 0], a.x, pr1);
                    pr1 = dot2acc(w1[4 * u + 1], a.y, pr1);
                    pr1 = dot2acc(w1[4 * u + 2], a.z, pr1);
                    pr1 = dot2acc(w1[4 * u + 3], a.w, pr1);
                    pz1 = dot2acc(w1[32 + 4 * u + 0], a.x, pz1);
                    pz1 = dot2acc(w1[32 + 4 * u + 1], a.y, pz1);
                    pz1 = dot2acc(w1[32 + 4 * u + 2], a.z, pz1);
                    pz1 = dot2acc(w1[32 + 4 * u + 3], a.w, pz1);
                } else {
                    pr0 = dot2acc(w1[4 * u + 0], a.x, pr0);
                    pr0 = dot2acc(w1[4 * u + 1], a.y, pr0);
                    pr0 = dot2acc(w1[4 * u + 2], a.z, pr0);
                    pr0 = dot2acc(w1[4 * u + 3], a.w, pr0);
                    pz0 = dot2acc(w1[32 + 4 * u + 0], a.x, pz0);
                    pz0 = dot2acc(w1[32 + 4 * u + 1], a.y, pz0);
                    pz0 = dot2acc(w1[32 + 4 * u + 2], a.z, pz0);
                    pz0 = dot2acc(w1[32 + 4 * u + 3], a.w, pz0);
                }
            }
        }
        float pr = pr0 + pr1, pz = pz0 + pz1;
        pr += __shfl_xor(pr, 16, 64); pr += __shfl_xor(pr, 32, 64);
        pz += __shfl_xor(pz, 16, 64); pz += __shfl_xor(pz, 32, 64);
        const float mr = pr, mz = pz;

        float vr[8] = {mr * mr, mz * mz, mr * uxr, mz * uxz,
                       mr * br, mz * bz, h * uxh, h * bh};
        bredX<8>(vr, redbuf[0], tid);
        const float S_mr2 = 0.25f * vr[0], S_mz2 = 0.25f * vr[1];
        const float S_mru = 0.25f * vr[2], S_mzu = 0.25f * vr[3];
        const float S_mrb = 0.25f * vr[4], S_mzb = 0.25f * vr[5];
        const float S_huxh = 0.25f * vr[6], S_hbh = 0.25f * vr[7];

        float r_t, z_t;
        {   // --- r gate ---
            float mxn = fmaxf(sqrtf(S_mr2), MINN);
            float tk = tan_k_(mxn * axh, sk, rsk);
            float f = tk * frcp_(mxn);
            float x2 = f * f * S_mr2, y2 = unr * unr, xy = f * S_mru;
            float a = 1.f - 2.f * k * xy - k * y2;
            float bq = 1.f + k * x2;
            float rd = frcp_(fmaxf(1.f - 2.f * k * xy + k * k * x2 * y2, MINN));
            float c1 = (a * f * mr + bq * uxr) * rd;
            float Sc12 = (a * a * x2 + 2.f * a * bq * xy + bq * bq * y2) * (rd * rd);
            float Sc1b = (a * f * S_mrb + bq * S_ubr) * rd;
            float g = 1.f - 2.f * k * Sc1b - k * bn2r;
            float dl = 1.f + k * Sc12;
            float re = frcp_(fmaxf(1.f - 2.f * k * Sc1b + k * k * Sc12 * bn2r, MINN));
            float c2 = (g * c1 + dl * br) * re;
            float Sc22 = (g * g * Sc12 + 2.f * g * dl * Sc1b + dl * dl * bn2r) * (re * re);
            float yn = fmaxf(sqrtf(Sc22), MINN);
            float lr = artan_k_(yn, sk, rsk) * frcp_(yn) * c2;
            r_t = sigm_(lr);
        }
        {   // --- z gate ---
            float mxn = fmaxf(sqrtf(S_mz2), MINN);
            float tk = tan_k_(mxn * axh, sk, rsk);
            float f = tk * frcp_(mxn);
            float x2 = f * f * S_mz2, y2 = unz * unz, xy = f * S_mzu;
            float a = 1.f - 2.f * k * xy - k * y2;
            float bq = 1.f + k * x2;
            float rd = frcp_(fmaxf(1.f - 2.f * k * xy + k * k * x2 * y2, MINN));
            float c1 = (a * f * mz + bq * uxz) * rd;
            float Sc12 = (a * a * x2 + 2.f * a * bq * xy + bq * bq * y2) * (rd * rd);
            float Sc1b = (a * f * S_mzb + bq * S_ubz) * rd;
            float g = 1.f - 2.f * k * Sc1b - k * bn2z;
            float dl = 1.f + k * Sc12;
            float re = frcp_(fmaxf(1.f - 2.f * k * Sc1b + k * k * Sc12 * bn2z, MINN));
            float c2 = (g * c1 + dl * bz) * re;
            float Sc22 = (g * g * Sc12 + 2.f * g * dl * Sc1b + dl * dl * bn2z) * (re * re);
            float yn = fmaxf(sqrtf(Sc22), MINN);
            float lz = artan_k_(yn, sk, rsk) * frcp_(yn) * c2;
            z_t = sigm_(lz);
        }

        // ---- rh: publish UNSCALED wx; merge S_wx2 reduction into same barrier ----
        float wx = r_t * hy;
        if (lane < 16) ((half_t*)rh2S)[p] = (half_t)wx;
        {
            float s1v = wsum63_(wx * wx);
            if (lane == 63) redbuf[1][wave] = s1v;
        }
        __syncthreads();  // B_B: rh/wx ready + partials ready

        float part1 = gsum16_(redbuf[1][lane & 15]);
        const float S_wx2 = 0.25f * rdlane_(part1, 15);
        float wxt = sqrtf(S_wx2);
        float wxn = fmaxf(wxt, MINN);
        float tkw = tan_k_(wxn * axh, sk, rsk);
        float fw = tkw * frcp_(wxn);      // rh = fw * wx (block scalar)
        float rhn = tkw * (wxt * frcp_(wxn));

        // ---- stage-2 matvec (h gate), quarter-split, LDS weights ----
        float q0 = 0.f, q1 = 0.f;
        {
            const uint4* rp = (const uint4*)rh2S + 8 * ph;
#pragma unroll
            for (int u = 0; u < 8; ++u) {
                uint4 wv = whhS[(8 * ph + u) * 256 + p];
                uint4 rv = rp[u];
                if (u & 1) {
                    q1 = dot2acc(wv.x, rv.x, q1);
                    q1 = dot2acc(wv.y, rv.y, q1);
                    q1 = dot2acc(wv.z, rv.z, q1);
                    q1 = dot2acc(wv.w, rv.w, q1);
                } else {
                    q0 = dot2acc(wv.x, rv.x, q0);
                    q0 = dot2acc(wv.y, rv.y, q0);
                    q0 = dot2acc(wv.z, rv.z, q0);
                    q0 = dot2acc(wv.w, rv.w, q0);
                }
            }
        }
        float qq = q0 + q1;
        qq += __shfl_xor(qq, 16, 64); qq += __shfl_xor(qq, 32, 64);
        const float mh = fw * qq;

        float v4b[4] = {mh * mh, mh * uxh, mh * bh, hy * mh};
        bredX<4>(v4b, redbuf[0], tid);
        const float S_mh2 = 0.25f * v4b[0], S_mhu = 0.25f * v4b[1];
        const float S_mhb = 0.25f * v4b[2], S_hymh = 0.25f * v4b[3];

        float wz, Sdelta2;
        {
            float xnrh = fmaxf(rhn, MINN);
            float axrh = artan_k_(xnrh, sk, rsk) * frcp_(xnrh);
            float mxn = fmaxf(sqrtf(S_mh2), MINN);
            float tk = tan_k_(mxn * axrh, sk, rsk);
            float f = tk * frcp_(mxn);
            float x2 = f * f * S_mh2, y2 = unh * unh, xy = f * S_mhu;
            float a = 1.f - 2.f * k * xy - k * y2;
            float bq = 1.f + k * x2;
            float rd = frcp_(fmaxf(1.f - 2.f * k * xy + k * k * x2 * y2, MINN));
            float c1 = (a * f * mh + bq * uxh) * rd;
            float Sc12 = (a * a * x2 + 2.f * a * bq * xy + bq * bq * y2) * (rd * rd);
            float Sc1b = (a * f * S_mhb + bq * S_ubh) * rd;
            float S_hyc1 = (a * f * S_hymh + bq * chy * S_huxh) * rd;
            float g = 1.f - 2.f * k * Sc1b - k * bn2h;
            float dl = 1.f + k * Sc12;
            float re = frcp_(fmaxf(1.f - 2.f * k * Sc1b + k * k * Sc12 * bn2h, MINN));
            float htl = (g * c1 + dl * bh) * re;
            float Shtl2 = (g * g * Sc12 + 2.f * g * dl * Sc1b + dl * dl * bn2h) * (re * re);
            float S_hyhtl = (g * S_hyc1 + dl * chy * S_hbh) * re;
            // delta = mobius_add(-hy, htl): xy_d = -S_hyhtl
            float ad = 1.f + 2.f * k * S_hyhtl - k * Shtl2;
            float bd = 1.f + k * Shy2;
            float rdd = frcp_(fmaxf(1.f + 2.f * k * S_hyhtl + k * k * Shy2 * Shtl2, MINN));
            float delta = (ad * (-hy) + bd * htl) * rdd;
            Sdelta2 = (ad * ad * Shy2 - 2.f * ad * bd * S_hyhtl + bd * bd * Shtl2) * (rdd * rdd);
            wz = z_t * delta;
        }
        float v2[2] = {wz * wz, hy * wz};
        bredX<2>(v2, redbuf[1], tid);
        const float S_wz2 = 0.25f * v2[0], S_hywz = 0.25f * v2[1];

        {
            float dnc = fmaxf(sqrtf(Sdelta2), MINN);
            float axd = artan_k_(dnc, sk, rsk) * frcp_(dnc);
            float wzt = sqrtf(S_wz2);
            float wznc = fmaxf(wzt, MINN);
            float tkzd = tan_k_(wznc * axd, sk, rsk);
            float fz = tkzd * frcp_(wznc);
            float zd = fz * wz;
            float zdn2 = fz * fz * S_wz2;
            float S_hyzd = fz * S_hywz;
            float an = 1.f - 2.f * k * S_hyzd - k * zdn2;
            float bn_ = 1.f + k * Shy2;
            float rdn = frcp_(fmaxf(1.f - 2.f * k * S_hyzd + k * k * Shy2 * zdn2, MINN));
            float hnew = (an * hy + bn_ * zd) * rdn;
            float Shnew2 = (an * an * Shy2 + 2.f * an * bn_ * S_hyzd + bn_ * bn_ * zdn2) * (rdn * rdn);
            float yn = fmaxf(sqrtf(Shnew2), MINN);
            float ayn = artan_k_(yn, sk, rsk) * frcp_(yn);
            float outv = ayn * hnew;
            if (lane < 16) myout[(size_t)t * stride_t + p] = outv;
            h = outv;
            S_h2 = ayn * ayn * Shnew2;  // carried, no reduction needed
        }
    }
    if (lane < 16) hcar[bb * 256 + p] = h;
}

// ---------- host launcher ----------
extern "C" void kernel_launch(void* const* d_in, const int* in_sizes, int n_in,
                              void* d_out, int out_size, void* d_ws, size_t ws_size,
                              hipStream_t stream) {
    const float* x    = (const float*)d_in[0];
    const float* kptr = (const float*)d_in[1];
    const float* h0   = (const float*)d_in[2];
    const float* wih0 = (const float*)d_in[3];
    const float* whh0 = (const float*)d_in[4];
    const float* b0   = (const float*)d_in[5];
    const float* wih1 = (const float*)d_in[6];
    const float* whh1 = (const float*)d_in[7];
    const float* b1   = (const float*)d_in[8];
    float* out = (float*)d_out;
    float* ws  = (float*)d_ws;

    const int B = 64, T = 1024, H = 256;
    const int CT = 64, NC = 16;
    const int RC = B * CT;  // 4096

    float* wt_ih0 = ws;
    float* wt_ih1 = wt_ih0 + 196608;
    uint32_t* w1pk0  = (uint32_t*)(wt_ih1 + 196608);  // 65536 u32 each
    uint32_t* w1pk1  = w1pk0 + 65536;
    uint32_t* whh2g0 = w1pk1 + 65536;                 // 32768 u32 each
    uint32_t* whh2g1 = whh2g0 + 32768;
    float* hcar  = (float*)(whh2g1 + 32768);
    float* s0    = hcar + 32768;
    float* ax0   = s0 + RC;
    float* s1    = ax0 + RC;
    float* ax1   = s1 + RC;
    float* uxn0  = ax1 + RC;
    float* uxn1  = uxn0 + 3 * RC;
    float* uxb0  = uxn1 + 3 * RC;
    float* uxb1  = uxb0 + 3 * RC;
    float* out0c = uxb1 + 3 * RC;
    float* mx0   = out0c + (size_t)RC * H;
    float* mx1   = mx0 + (size_t)RC * 768;

    float* hcar0 = hcar;
    float* hcar1 = hcar + (size_t)B * H;

    dim3 blk(256);
    kt_transpose<<<dim3(1536), blk, 0, stream>>>(wih0, wih1, wt_ih0, wt_ih1);
    kt_prep1<<<dim3(512), blk, 0, stream>>>(whh0, whh1, w1pk0, w1pk1);
    kt_prep2<<<dim3(256), blk, 0, stream>>>(whh0, whh1, whh2g0, whh2g1);
    kt_init<<<dim3(128), blk, 0, stream>>>(h0, hcar);

    const long long sbx = (long long)T * 256;
    const long long sbc = (long long)CT * 256;

    // ---- prologue: layer 0, chunk 0 ----
    {
        const float* xc = x;
        kt_rowscale<<<dim3(RC / 4), blk, 0, stream>>>(xc, sbx, s0, ax0, kptr, 0);
        kt_gemm<<<dim3(12, RC / 64), blk, 0, stream>>>(xc, sbx, s0, wt_ih0, mx0);
        kt_mscale<<<dim3(RC * 3 / 4), blk, 0, stream>>>(mx0, ax0, uxn0, uxb0, b0, kptr);
        kt_scan2<<<dim3(B), dim3(1024), 0, stream>>>(
            mx0, uxn0, uxb0, w1pk0, whh2g0, b0, hcar0, out0c, sbc, 256LL,
            mx0, uxn0, uxb0, w1pk0, whh2g0, b0, hcar0, out0c, sbc, 256LL,
            kptr, CT, B);
    }
    // ---- steady state: dual scans (L0 chunk c || L1 chunk c-1) ----
    for (int c = 1; c < NC; ++c) {
        const float* xc = x + (size_t)c * CT * 256;
        kt_rowscale<<<dim3(RC / 4), blk, 0, stream>>>(xc, sbx, s0, ax0, kptr, 0);
        kt_gemm<<<dim3(12, RC / 64), blk, 0, stream>>>(xc, sbx, s0, wt_ih0, mx0);
        kt_mscale<<<dim3(RC * 3 / 4), blk, 0, stream>>>(mx0, ax0, uxn0, uxb0, b0, kptr);
        kt_rowscale<<<dim3(RC / 4), blk, 0, stream>>>(out0c, sbc, s1, ax1, kptr, 1);
        kt_gemm<<<dim3(12, RC / 64), blk, 0, stream>>>(out0c, sbc, s1, wt_ih1, mx1);
        kt_mscale<<<dim3(RC * 3 / 4), blk, 0, stream>>>(mx1, ax1, uxn1, uxb1, b1, kptr);
        kt_scan2<<<dim3(2 * B), dim3(1024), 0, stream>>>(
            mx0, uxn0, uxb0, w1pk0, whh2g0, b0, hcar0, out0c, sbc, 256LL,
            mx1, uxn1, uxb1, w1pk1, whh2g1, b1, hcar1,
            out + (size_t)(c - 1) * CT * B * H, 256LL, (long long)B * H,
            kptr, CT, B);
    }
    // ---- epilogue: layer 1, chunk NC-1 ----
    {
        kt_rowscale<<<dim3(RC / 4), blk, 0, stream>>>(out0c, sbc, s1, ax1, kptr, 1);
        kt_gemm<<<dim3(12, RC / 64), blk, 0, stream>>>(out0c, sbc, s1, wt_ih1, mx1);
        kt_mscale<<<dim3(RC * 3 / 4), blk, 0, stream>>>(mx1, ax1, uxn1, uxb1, b1, kptr);
        kt_scan2<<<dim3(B), dim3(1024), 0, stream>>>(
            mx1, uxn1, uxb1, w1pk1, whh2g1, b1, hcar1,
            out + (size_t)(NC - 1) * CT * B * H, 256LL, (long long)B * H,
            mx1, uxn1, uxb1, w1pk1, whh2g1, b1, hcar1,
            out + (size_t)(NC - 1) * CT * B * H, 256LL, (long long)B * H,
            kptr, CT, B);
    }
    kt_final<<<dim3(128), blk, 0, stream>>>(hcar, out + (size_t)T * B * H);
}

// Round 10
// 6133.709 us; speedup vs baseline: 2.1735x; 1.4530x over previous
//
#include <hip/hip_runtime.h>
#include <cstdint>
#include <cstddef>

#define MINN 1e-15f
#define EPSA 1e-7f
#define C_L2E 1.44269504088896341f
#define C_LN2 0.69314718055994531f

typedef _Float16 half_t;
typedef _Float16 half2_t __attribute__((ext_vector_type(2)));

#if defined(__has_builtin)
#if __has_builtin(__builtin_amdgcn_update_dpp) && __has_builtin(__builtin_amdgcn_readlane)
#define USE_DPP 1
#endif
#endif

// ---------- fast-math helpers (native, ~1 ulp) ----------
__device__ __forceinline__ float fexp2_(float x) {
#if defined(__has_builtin) && __has_builtin(__builtin_amdgcn_exp2f)
    return __builtin_amdgcn_exp2f(x);
#else
    return exp2f(x);
#endif
}
__device__ __forceinline__ float flog2_(float x) {
#if defined(__has_builtin) && __has_builtin(__builtin_amdgcn_logf)
    return __builtin_amdgcn_logf(x);
#else
    return log2f(x);
#endif
}
__device__ __forceinline__ float frcp_(float x) {
#if defined(__has_builtin) && __has_builtin(__builtin_amdgcn_rcpf)
    return __builtin_amdgcn_rcpf(x);
#else
    return 1.f / x;
#endif
}
__device__ __forceinline__ float tan_k_(float u, float sk, float rsk) {
    float a = fminf(fmaxf(sk * u, -15.f), 15.f);
    float t = fexp2_(a * (2.f * C_L2E));
    return (1.f - 2.f * frcp_(t + 1.f)) * rsk;
}
__device__ __forceinline__ float artan_k_(float u, float sk, float rsk) {
    float a = fminf(fmaxf(sk * u, -1.f + EPSA), 1.f - EPSA);
    return flog2_((1.f + a) * frcp_(1.f - a)) * (0.5f * C_LN2) * rsk;
}
__device__ __forceinline__ float sigm_(float x) {
    return frcp_(1.f + fexp2_(-x * C_L2E));
}
__device__ __forceinline__ float wave_sum(float v) {
#pragma unroll
    for (int off = 32; off; off >>= 1) v += __shfl_xor(v, off, 64);
    return v;
}

// ---------- DPP reduction primitives (VALU pipe, not DS) ----------
#ifdef USE_DPP
template <int CTRL, int RM, int BM>
__device__ __forceinline__ float dppmov_(float x) {
    return __builtin_bit_cast(float,
        __builtin_amdgcn_update_dpp(0, __builtin_bit_cast(int, x), CTRL, RM, BM, false));
}
#endif
// full 64-lane sum; result valid in lane 63 (fallback: all lanes)
__device__ __forceinline__ float wsum63_(float x) {
#ifdef USE_DPP
    x += dppmov_<0x111, 0xf, 0xf>(x);  // row_shr:1
    x += dppmov_<0x112, 0xf, 0xf>(x);  // row_shr:2
    x += dppmov_<0x114, 0xf, 0xe>(x);  // row_shr:4
    x += dppmov_<0x118, 0xf, 0xc>(x);  // row_shr:8
    x += dppmov_<0x142, 0xa, 0xf>(x);  // row_bcast:15
    x += dppmov_<0x143, 0xc, 0xf>(x);  // row_bcast:31 -> lane63 = total
    return x;
#else
    return wave_sum(x);
#endif
}
// 8-lane group prefix sum; result valid in lane 8n+7 (fallback: all lanes)
__device__ __forceinline__ float gsum8_(float x) {
#ifdef USE_DPP
    x += dppmov_<0x111, 0xf, 0xf>(x);
    x += dppmov_<0x112, 0xf, 0xf>(x);
    x += dppmov_<0x114, 0xf, 0xe>(x);
    return x;
#else
    x += __shfl_xor(x, 1, 64);
    x += __shfl_xor(x, 2, 64);
    x += __shfl_xor(x, 4, 64);
    return x;
#endif
}
__device__ __forceinline__ float rdlane_(float x, int l) {
#ifdef USE_DPP
    return __builtin_bit_cast(float,
        __builtin_amdgcn_readlane(__builtin_bit_cast(int, x), l));
#else
    return __shfl(x, l, 64);
#endif
}
// block(512)-wide reduce of N values via DPP + 1 LDS round trip.
// ONE internal barrier; caller alternates redbuf between consecutive uses.
template <int N>
__device__ __forceinline__ void bredX(float* v, float* redbuf, int tid) {
    const int lane = tid & 63, wave = tid >> 6;
#pragma unroll
    for (int n = 0; n < N; ++n) {
        float s = wsum63_(v[n]);
        if (lane == 63) redbuf[n * 8 + wave] = s;
    }
    __syncthreads();
    float part = redbuf[lane & (8 * N - 1)];
    part = gsum8_(part);
#pragma unroll
    for (int n = 0; n < N; ++n) v[n] = rdlane_(part, 8 * n + 7);
}

// f16 pair dot-accumulate
__device__ __forceinline__ float dot2acc(uint32_t w, uint32_t h, float acc) {
#if defined(__has_builtin) && __has_builtin(__builtin_amdgcn_fdot2)
    return __builtin_amdgcn_fdot2(__builtin_bit_cast(half2_t, w),
                                  __builtin_bit_cast(half2_t, h), acc, false);
#else
    half2_t a = __builtin_bit_cast(half2_t, w);
    half2_t b = __builtin_bit_cast(half2_t, h);
    acc = fmaf((float)a[0], (float)b[0], acc);
    return fmaf((float)a[1], (float)b[1], acc);
#endif
}

// ---------- K1: transpose 2 ih weight matrices [768x256] -> [256x768] ----------
__global__ __launch_bounds__(256) void kt_transpose(
    const float* __restrict__ a0, const float* __restrict__ a1,
    float* __restrict__ o0, float* __restrict__ o1) {
    int idx = blockIdx.x * 256 + threadIdx.x;
    int m = idx / 196608, rem = idx % 196608;
    int j = rem >> 8, kk = rem & 255;
    const float* in = (m == 0) ? a0 : a1;
    float* outp     = (m == 0) ? o0 : o1;
    outp[kk * 768 + j] = in[j * 256 + kk];
}

// ---------- prep1: pack stage-1 (W_hr,W_hz) f16 per-thread fragments ----------
// HALF-WAVE pair layout: thread t: lane=t&63, wave=t>>6,
//   p = wave*32 + (lane&31), ph = lane>>5.
__global__ __launch_bounds__(256) void kt_prep1(
    const float* __restrict__ whh0, const float* __restrict__ whh1,
    uint32_t* __restrict__ p0, uint32_t* __restrict__ p1) {
    int idx = blockIdx.x * 256 + threadIdx.x;  // 131072
    int l = idx >> 16, e = idx & 65535;
    int r4 = e >> 11, rem = e & 2047;
    int t = rem >> 2, m = r4 * 4 + (rem & 3);
    int lane = t & 63, wave = t >> 6;
    int p = wave * 32 + (lane & 31), ph = lane >> 5;
    int g = m >> 6, mi = m & 63;
    int row = g ? (512 + p) : p;
    int i = ph * 128 + 2 * mi;
    const float* w = l ? whh1 : whh0;
    half2_t hv;
    hv[0] = (half_t)w[row * 256 + i];
    hv[1] = (half_t)w[row * 256 + i + 1];
    (l ? p1 : p0)[e] = __builtin_bit_cast(uint32_t, hv);
}

// ---------- prep2: pack stage-2 (W_hh_) f16 [i2][j] half2 ----------
__global__ __launch_bounds__(256) void kt_prep2(
    const float* __restrict__ whh0, const float* __restrict__ whh1,
    uint32_t* __restrict__ p0, uint32_t* __restrict__ p1) {
    int idx = blockIdx.x * 256 + threadIdx.x;  // 65536
    int l = idx >> 15, e = idx & 32767;
    int i2 = e >> 8, j = e & 255;
    const float* w = l ? whh1 : whh0;
    half2_t hv;
    hv[0] = (half_t)w[(256 + j) * 256 + 2 * i2];
    hv[1] = (half_t)w[(256 + j) * 256 + 2 * i2 + 1];
    (l ? p1 : p0)[e] = __builtin_bit_cast(uint32_t, hv);
}

// ---------- init / final ----------
__global__ __launch_bounds__(256) void kt_init(
    const float* __restrict__ h0, float* __restrict__ hcar) {
    int i = blockIdx.x * 256 + threadIdx.x;
    hcar[i] = h0[i];
}
__global__ __launch_bounds__(256) void kt_final(
    const float* __restrict__ hcar, float* __restrict__ dst) {
    int i = blockIdx.x * 256 + threadIdx.x;
    dst[i] = hcar[i];
}

// ---------- fused rowscale+gemm: C = diag(s)*A @ Bt ; also writes ax_arr ----
// mode 0: s=tan_k(n)/n (expmap0), xn=tan_k(n);  mode 1: s=1, xn=max(n,MINN).
__global__ __launch_bounds__(256) void kt_gemm(
    const float* __restrict__ A, long long strideB,
    const float* __restrict__ Bt, float* __restrict__ C,
    float* __restrict__ ax_arr, const float* __restrict__ kptr, int mode) {
    __shared__ float As[16][68];
    __shared__ float Bs[16][68];
    __shared__ float sS[64];
    int tid = threadIdx.x;
    int row0 = blockIdx.y * 64, col0 = blockIdx.x * 64;

    // ---- fused rowscale prologue: row t>>2, quarter t&3 (4 lanes per row) ----
    {
        float kk = kptr[0], sk = sqrtf(-kk), rsk = frcp_(sk);
        int row = tid >> 2, q = tid & 3;
        int rc = row0 + row;
        size_t base = (size_t)(rc >> 6) * strideB + (size_t)(rc & 63) * 256 + q * 64;
        float n2 = 0.f;
#pragma unroll
        for (int u = 0; u < 16; ++u) {
            float4 v = *(const float4*)&A[base + u * 4];
            n2 += v.x * v.x + v.y * v.y + v.z * v.z + v.w * v.w;
        }
        n2 += __shfl_xor(n2, 1, 64);
        n2 += __shfl_xor(n2, 2, 64);
        float n = sqrtf(n2);
        float s, xn;
        if (mode == 0) {
            float nrm = fmaxf(n, MINN);
            float tk = tan_k_(nrm, sk, rsk);
            s = tk * frcp_(nrm);
            xn = fmaxf(tk * (n * frcp_(nrm)), MINN);
        } else {
            s = 1.f;
            xn = fmaxf(n, MINN);
        }
        float ax = artan_k_(xn, sk, rsk) * frcp_(xn);
        if (q == 0) { sS[row] = s; ax_arr[rc] = ax; }
    }

    int ty = tid >> 4, tx = tid & 15;
    int ra = tid >> 2, kq = tid & 3;
    int kb = tid >> 4, cq = tid & 15;
    float acc[4][4] = {};
    __syncthreads();
#pragma unroll 1
    for (int kt = 0; kt < 16; ++kt) {
        int k0 = kt * 16;
        int rc = row0 + ra;
        size_t aoff = (size_t)(rc >> 6) * strideB + (size_t)(rc & 63) * 256 + k0 + kq * 4;
        float4 av = *(const float4*)&A[aoff];
        float sc = sS[ra];
        float4 bv = *(const float4*)&Bt[(size_t)(k0 + kb) * 768 + col0 + cq * 4];
        As[kq * 4 + 0][ra] = av.x * sc;
        As[kq * 4 + 1][ra] = av.y * sc;
        As[kq * 4 + 2][ra] = av.z * sc;
        As[kq * 4 + 3][ra] = av.w * sc;
        *(float4*)&Bs[kb][cq * 4] = bv;
        __syncthreads();
#pragma unroll
        for (int kk = 0; kk < 16; ++kk) {
            float4 a4 = *(const float4*)&As[kk][ty * 4];
            float4 b4 = *(const float4*)&Bs[kk][tx * 4];
            float aa[4] = {a4.x, a4.y, a4.z, a4.w};
            float bb[4] = {b4.x, b4.y, b4.z, b4.w};
#pragma unroll
            for (int i = 0; i < 4; ++i)
#pragma unroll
                for (int j = 0; j < 4; ++j)
                    acc[i][j] = fmaf(aa[i], bb[j], acc[i][j]);
        }
        __syncthreads();
    }
#pragma unroll
    for (int i = 0; i < 4; ++i) {
        size_t row = (size_t)row0 + ty * 4 + i;
        *(float4*)&C[row * 768 + col0 + tx * 4] =
            make_float4(acc[i][0], acc[i][1], acc[i][2], acc[i][3]);
    }
}

// scales mx in place, stores ||Ux|| and (Ux . bias) per (row,gate)
__global__ __launch_bounds__(256) void kt_mscale(
    float* __restrict__ mx, const float* __restrict__ ax_arr,
    float* __restrict__ uxn, float* __restrict__ uxb,
    const float* __restrict__ bias, const float* __restrict__ kptr) {
    int lane = threadIdx.x & 63;
    int p = blockIdx.x * 4 + (threadIdx.x >> 6);
    int r = p / 3;
    int g = p - r * 3;
    float k = kptr[0], sk = sqrtf(-k), rsk = frcp_(sk);
    float* ptr = mx + (size_t)r * 768 + g * 256 + lane * 4;
    float4 v = *(const float4*)ptr;
    float4 b4 = *(const float4*)&bias[g * 256 + lane * 4];
    float n2 = wave_sum(v.x * v.x + v.y * v.y + v.z * v.z + v.w * v.w);
    float vb = wave_sum(v.x * b4.x + v.y * b4.y + v.z * b4.z + v.w * b4.w);
    float nt = sqrtf(n2);
    float mxn = fmaxf(nt, MINN);
    float arg = mxn * ax_arr[r];
    float tk = tan_k_(arg, sk, rsk);
    float f = tk * frcp_(mxn);
    v.x *= f; v.y *= f; v.z *= f; v.w *= f;
    *(float4*)ptr = v;
    if (lane == 0) { uxn[p] = tk * (nt * frcp_(mxn)); uxb[p] = f * vb; }
}

// ---------- K6: persistent-weight scan, dual-role, half-wave pair layout ----------
// Thread: lane=tid&63, wave=tid>>6; p = wave*32+(lane&31), ph = lane>>5.
// Pair partners are lanes (l, l^32) in the same wave -> shfl_xor(32).
// Block sums duplicated per pair -> scale 0.5 after reduce.
__global__ __launch_bounds__(512, 1) void kt_scan2(
    const float* __restrict__ Ux_0, const float* __restrict__ uxn_0,
    const float* __restrict__ uxb_0,
    const uint32_t* __restrict__ w1pk_0, const uint32_t* __restrict__ whh2g_0,
    const float* __restrict__ bias_0, float* __restrict__ hcar_0,
    float* __restrict__ out_0, long long sb_0, long long st_0,
    const float* __restrict__ Ux_1, const float* __restrict__ uxn_1,
    const float* __restrict__ uxb_1,
    const uint32_t* __restrict__ w1pk_1, const uint32_t* __restrict__ whh2g_1,
    const float* __restrict__ bias_1, float* __restrict__ hcar_1,
    float* __restrict__ out_1, long long sb_1, long long st_1,
    const float* __restrict__ kptr, int Tc, int nrole0) {
    __shared__ uint4 whhS[8192];       // 128 KiB: W_hh_ f16, [i2-quad][j]
    __shared__ uint32_t hy2S[128];     // hy as 128 half2
    __shared__ uint32_t rh2S[128];     // wx (unscaled rh) as 128 half2
    __shared__ float redbuf[2][64];    // double-buffered reduce scratch

    const int tid = threadIdx.x;
    const int role = (blockIdx.x >= nrole0) ? 1 : 0;
    const int bb = role ? (int)blockIdx.x - nrole0 : (int)blockIdx.x;

    const float* Ux      = role ? Ux_1 : Ux_0;
    const float* uxn     = role ? uxn_1 : uxn_0;
    const float* uxb     = role ? uxb_1 : uxb_0;
    const uint32_t* w1pk = role ? w1pk_1 : w1pk_0;
    const uint32_t* whh2g= role ? whh2g_1 : whh2g_0;
    const float* bias    = role ? bias_1 : bias_0;
    float* hcar          = role ? hcar_1 : hcar_0;
    float* outbase       = role ? out_1 : out_0;
    const long long stride_b = role ? sb_1 : sb_0;
    const long long stride_t = role ? st_1 : st_0;

    const int lane = tid & 63, wave = tid >> 6;
    const int p = wave * 32 + (lane & 31), ph = lane >> 5;
    const float k = kptr[0], sk = sqrtf(-k), rsk = frcp_(sk);

    // stage-2 weights -> LDS
    for (int idx = tid; idx < 32768; idx += 512) {
        uint32_t v = whh2g[idx];
        int i2 = idx >> 8, col = idx & 255;
        ((uint32_t*)whhS)[((i2 >> 2) * 256 + col) * 4 + (i2 & 3)] = v;
    }
    // stage-1 weights -> registers (128 u32 = 256 f16)
    uint32_t w1[128];
    {
        const uint4* wp = (const uint4*)w1pk;  // [32][512] uint4
#pragma unroll
        for (int r4 = 0; r4 < 32; ++r4) {
            uint4 v = wp[r4 * 512 + tid];
            w1[4 * r4 + 0] = v.x; w1[4 * r4 + 1] = v.y;
            w1[4 * r4 + 2] = v.z; w1[4 * r4 + 3] = v.w;
        }
    }

    const float br = bias[p], bh = bias[256 + p], bz = bias[512 + p];
    float h = hcar[bb * 256 + p];
    __syncthreads();  // whhS ready
    float v4[4] = {br * br, bh * bh, bz * bz, h * h};
    bredX<4>(v4, redbuf[0], tid);
    const float bn2r = 0.5f * v4[0], bn2h = 0.5f * v4[1], bn2z = 0.5f * v4[2];
    float S_h2 = 0.5f * v4[3];

    float* myout = outbase + (size_t)bb * stride_b;
    const float* uxpb = Ux + (size_t)bb * Tc * 768;
    const float* unpb = uxn + (size_t)bb * Tc * 3;
    const float* ubpb = uxb + (size_t)bb * Tc * 3;

    // prefetch step 0
    float puxr = uxpb[p], puxh = uxpb[256 + p], puxz = uxpb[512 + p];
    float punr = unpb[0], punh = unpb[1], punz = unpb[2];
    float pubr = ubpb[0], pubh = ubpb[1], pubz = ubpb[2];

    for (int t = 0; t < Tc; ++t) {
        const float uxr = puxr, uxh = puxh, uxz = puxz;
        const float unr = punr, unh = punh, unz = punz;
        const float S_ubr = pubr, S_ubh = pubh, S_ubz = pubz;

        // ---- expmap0(h): scalars from carried S_h2 ----
        float hn = sqrtf(S_h2);
        float nrm = fmaxf(hn, MINN);
        float tk0 = tan_k_(nrm, sk, rsk);
        float chy = tk0 * frcp_(nrm);
        float hy = chy * h;
        float Shy2 = chy * chy * S_h2;
        float xnh = fmaxf(tk0 * (hn * frcp_(nrm)), MINN);
        float axh = artan_k_(xnh, sk, rsk) * frcp_(xnh);
        if (ph == 0) ((half_t*)hy2S)[p] = (half_t)hy;
        __syncthreads();  // B1: hy ready

        // prefetch next step (hidden under matvec + reductions)
        if (t + 1 < Tc) {
            const float* uxp2 = uxpb + (size_t)(t + 1) * 768;
            puxr = uxp2[p]; puxh = uxp2[256 + p]; puxz = uxp2[512 + p];
            const float* unp2 = unpb + (size_t)(t + 1) * 3;
            punr = unp2[0]; punh = unp2[1]; punz = unp2[2];
            const float* ubp2 = ubpb + (size_t)(t + 1) * 3;
            pubr = ubp2[0]; pubh = ubp2[1]; pubz = ubp2[2];
        }

        // ---- stage-1 matvec (r,z), half-split, 4-deep accumulators ----
        float prA[4] = {0.f, 0.f, 0.f, 0.f};
        float pzA[4] = {0.f, 0.f, 0.f, 0.f};
        {
            const uint4* hp = (const uint4*)hy2S + ph * 16;
#pragma unroll
            for (int c4 = 0; c4 < 4; ++c4) {
                uint32_t hv[16];
#pragma unroll
                for (int u = 0; u < 4; ++u) {
                    uint4 v = hp[c4 * 4 + u];
                    hv[4 * u + 0] = v.x; hv[4 * u + 1] = v.y;
                    hv[4 * u + 2] = v.z; hv[4 * u + 3] = v.w;
                }
#pragma unroll
                for (int m = 0; m < 16; ++m) {
                    prA[c4] = dot2acc(w1[c4 * 16 + m], hv[m], prA[c4]);
                    pzA[c4] = dot2acc(w1[64 + c4 * 16 + m], hv[m], pzA[c4]);
                }
            }
        }
        float pr = (prA[0] + prA[1]) + (prA[2] + prA[3]);
        float pz = (pzA[0] + pzA[1]) + (pzA[2] + pzA[3]);
        const float mr = pr + __shfl_xor(pr, 32, 64);
        const float mz = pz + __shfl_xor(pz, 32, 64);

        float vr[8] = {mr * mr, mz * mz, mr * uxr, mz * uxz,
                       mr * br, mz * bz, h * uxh, h * bh};
        bredX<8>(vr, redbuf[0], tid);
        const float S_mr2 = 0.5f * vr[0], S_mz2 = 0.5f * vr[1];
        const float S_mru = 0.5f * vr[2], S_mzu = 0.5f * vr[3];
        const float S_mrb = 0.5f * vr[4], S_mzb = 0.5f * vr[5];
        const float S_huxh = 0.5f * vr[6], S_hbh = 0.5f * vr[7];

        // ---- gates r,z: ONE chain per lane; ph=0 lanes do r, ph=1 do z ----
        // (input-select; bit-identical to running both chains everywhere)
        const float m_   = ph ? mz    : mr;
        const float S2_  = ph ? S_mz2 : S_mr2;
        const float Su_  = ph ? S_mzu : S_mru;
        const float Sb_  = ph ? S_mzb : S_mrb;
        const float Sub_ = ph ? S_ubz : S_ubr;
        const float bn2_ = ph ? bn2z  : bn2r;
        const float un_  = ph ? unz   : unr;
        const float ux_  = ph ? uxz   : uxr;
        const float b_   = ph ? bz    : br;
        float g_own;
        {
            float mxn = fmaxf(sqrtf(S2_), MINN);
            float tk = tan_k_(mxn * axh, sk, rsk);
            float f = tk * frcp_(mxn);
            float x2 = f * f * S2_, y2 = un_ * un_, xy = f * Su_;
            float a = 1.f - 2.f * k * xy - k * y2;
            float bq = 1.f + k * x2;
            float rd = frcp_(fmaxf(1.f - 2.f * k * xy + k * k * x2 * y2, MINN));
            float c1 = (a * f * m_ + bq * ux_) * rd;
            float Sc12 = (a * a * x2 + 2.f * a * bq * xy + bq * bq * y2) * (rd * rd);
            float Sc1b = (a * f * Sb_ + bq * Sub_) * rd;
            float g = 1.f - 2.f * k * Sc1b - k * bn2_;
            float dl = 1.f + k * Sc12;
            float re = frcp_(fmaxf(1.f - 2.f * k * Sc1b + k * k * Sc12 * bn2_, MINN));
            float c2 = (g * c1 + dl * b_) * re;
            float Sc22 = (g * g * Sc12 + 2.f * g * dl * Sc1b + dl * dl * bn2_) * (re * re);
            float yn = fmaxf(sqrtf(Sc22), MINN);
            float lg = artan_k_(yn, sk, rsk) * frcp_(yn) * c2;
            g_own = sigm_(lg);
        }
        const float g_oth = __shfl_xor(g_own, 32, 64);
        const float r_t = ph ? g_oth : g_own;
        const float z_t = ph ? g_own : g_oth;

        // ---- rh: publish UNSCALED wx; merge S_wx2 reduction into same barrier ----
        float wx = r_t * hy;
        if (ph == 0) ((half_t*)rh2S)[p] = (half_t)wx;
        {
            float s1v = wsum63_(wx * wx);
            if (lane == 63) redbuf[1][wave] = s1v;
        }
        __syncthreads();  // B_B: rh/wx ready + v1 partials ready

        float part1 = gsum8_(redbuf[1][lane & 7]);
        const float S_wx2 = 0.5f * rdlane_(part1, 7);
        float wxt = sqrtf(S_wx2);
        float wxn = fmaxf(wxt, MINN);
        float tkw = tan_k_(wxn * axh, sk, rsk);
        float fw = tkw * frcp_(wxn);      // rh = fw * wx (fw is block scalar)
        float rhn = tkw * (wxt * frcp_(wxn));

        // ---- stage-2 matvec (h gate), half-split, 4-deep accumulators ----
        float qA[4] = {0.f, 0.f, 0.f, 0.f};
        {
            const uint4* rp = (const uint4*)rh2S + ph * 16;
#pragma unroll
            for (int u = 0; u < 16; ++u) {
                uint4 wv = whhS[(ph * 16 + u) * 256 + p];
                uint4 rv = rp[u];
                int s = u >> 2;
                qA[s] = dot2acc(wv.x, rv.x, qA[s]);
                qA[s] = dot2acc(wv.y, rv.y, qA[s]);
                qA[s] = dot2acc(wv.z, rv.z, qA[s]);
                qA[s] = dot2acc(wv.w, rv.w, qA[s]);
            }
        }
        float qq = (qA[0] + qA[1]) + (qA[2] + qA[3]);
        const float mh = fw * (qq + __shfl_xor(qq, 32, 64));

        float v4b[4] = {mh * mh, mh * uxh, mh * bh, hy * mh};
        bredX<4>(v4b, redbuf[0], tid);
        const float S_mh2 = 0.5f * v4b[0], S_mhu = 0.5f * v4b[1];
        const float S_mhb = 0.5f * v4b[2], S_hymh = 0.5f * v4b[3];

        float wz, Sdelta2;
        {
            float xnrh = fmaxf(rhn, MINN);
            float axrh = artan_k_(xnrh, sk, rsk) * frcp_(xnrh);
            float mxn = fmaxf(sqrtf(S_mh2), MINN);
            float tk = tan_k_(mxn * axrh, sk, rsk);
            float f = tk * frcp_(mxn);
            float x2 = f * f * S_mh2, y2 = unh * unh, xy = f * S_mhu;
            float a = 1.f - 2.f * k * xy - k * y2;
            float bq = 1.f + k * x2;
            float rd = frcp_(fmaxf(1.f - 2.f * k * xy + k * k * x2 * y2, MINN));
            float c1 = (a * f * mh + bq * uxh) * rd;
            float Sc12 = (a * a * x2 + 2.f * a * bq * xy + bq * bq * y2) * (rd * rd);
            float Sc1b = (a * f * S_mhb + bq * S_ubh) * rd;
            float S_hyc1 = (a * f * S_hymh + bq * chy * S_huxh) * rd;
            float g = 1.f - 2.f * k * Sc1b - k * bn2h;
            float dl = 1.f + k * Sc12;
            float re = frcp_(fmaxf(1.f - 2.f * k * Sc1b + k * k * Sc12 * bn2h, MINN));
            float htl = (g * c1 + dl * bh) * re;
            float Shtl2 = (g * g * Sc12 + 2.f * g * dl * Sc1b + dl * dl * bn2h) * (re * re);
            float S_hyhtl = (g * S_hyc1 + dl * chy * S_hbh) * re;
            // delta = mobius_add(-hy, htl): xy_d = -S_hyhtl
            float ad = 1.f + 2.f * k * S_hyhtl - k * Shtl2;
            float bd = 1.f + k * Shy2;
            float rdd = frcp_(fmaxf(1.f + 2.f * k * S_hyhtl + k * k * Shy2 * Shtl2, MINN));
            float delta = (ad * (-hy) + bd * htl) * rdd;
            Sdelta2 = (ad * ad * Shy2 - 2.f * ad * bd * S_hyhtl + bd * bd * Shtl2) * (rdd * rdd);
            wz = z_t * delta;
        }
        float v2[2] = {wz * wz, hy * wz};
        bredX<2>(v2, redbuf[1], tid);
        const float S_wz2 = 0.5f * v2[0], S_hywz = 0.5f * v2[1];

        {
            float dnc = fmaxf(sqrtf(Sdelta2), MINN);
            float axd = artan_k_(dnc, sk, rsk) * frcp_(dnc);
            float wzt = sqrtf(S_wz2);
            float wznc = fmaxf(wzt, MINN);
            float tkzd = tan_k_(wznc * axd, sk, rsk);
            float fz = tkzd * frcp_(wznc);
            float zd = fz * wz;
            float zdn2 = fz * fz * S_wz2;
            float S_hyzd = fz * S_hywz;
            float an = 1.f - 2.f * k * S_hyzd - k * zdn2;
            float bn_ = 1.f + k * Shy2;
            float rdn = frcp_(fmaxf(1.f - 2.f * k * S_hyzd + k * k * Shy2 * zdn2, MINN));
            float hnew = (an * hy + bn_ * zd) * rdn;
            float Shnew2 = (an * an * Shy2 + 2.f * an * bn_ * S_hyzd + bn_ * bn_ * zdn2) * (rdn * rdn);
            float yn = fmaxf(sqrtf(Shnew2), MINN);
            float ayn = artan_k_(yn, sk, rsk) * frcp_(yn);
            float outv = ayn * hnew;
            if (ph == 0) myout[(size_t)t * stride_t + p] = outv;
            h = outv;
            S_h2 = ayn * ayn * Shnew2;  // carried, no reduction needed
        }
    }
    if (ph == 0) hcar[bb * 256 + p] = h;
}

// ---------- host launcher ----------
extern "C" void kernel_launch(void* const* d_in, const int* in_sizes, int n_in,
                              void* d_out, int out_size, void* d_ws, size_t ws_size,
                              hipStream_t stream) {
    const float* x    = (const float*)d_in[0];
    const float* kptr = (const float*)d_in[1];
    const float* h0   = (const float*)d_in[2];
    const float* wih0 = (const float*)d_in[3];
    const float* whh0 = (const float*)d_in[4];
    const float* b0   = (const float*)d_in[5];
    const float* wih1 = (const float*)d_in[6];
    const float* whh1 = (const float*)d_in[7];
    const float* b1   = (const float*)d_in[8];
    float* out = (float*)d_out;
    float* ws  = (float*)d_ws;

    const int B = 64, T = 1024, H = 256;
    const int CT = 64, NC = 16;
    const int RC = B * CT;  // 4096

    float* wt_ih0 = ws;
    float* wt_ih1 = wt_ih0 + 196608;
    uint32_t* w1pk0  = (uint32_t*)(wt_ih1 + 196608);
    uint32_t* w1pk1  = w1pk0 + 65536;
    uint32_t* whh2g0 = w1pk1 + 65536;
    uint32_t* whh2g1 = whh2g0 + 32768;
    float* hcar  = (float*)(whh2g1 + 32768);
    float* ax0   = hcar + 32768;
    float* ax1   = ax0 + RC;
    float* uxn0  = ax1 + RC;
    float* uxn1  = uxn0 + 3 * RC;
    float* uxb0  = uxn1 + 3 * RC;
    float* uxb1  = uxb0 + 3 * RC;
    float* out0c = uxb1 + 3 * RC;
    float* mx0   = out0c + (size_t)RC * H;
    float* mx1   = mx0 + (size_t)RC * 768;

    float* hcar0 = hcar;
    float* hcar1 = hcar + (size_t)B * H;

    dim3 blk(256);
    kt_transpose<<<dim3(1536), blk, 0, stream>>>(wih0, wih1, wt_ih0, wt_ih1);
    kt_prep1<<<dim3(512), blk, 0, stream>>>(whh0, whh1, w1pk0, w1pk1);
    kt_prep2<<<dim3(256), blk, 0, stream>>>(whh0, whh1, whh2g0, whh2g1);
    kt_init<<<dim3(128), blk, 0, stream>>>(h0, hcar);

    const long long sbx = (long long)T * 256;
    const long long sbc = (long long)CT * 256;

    // ---- prologue: layer 0, chunk 0 ----
    {
        const float* xc = x;
        kt_gemm<<<dim3(12, RC / 64), blk, 0, stream>>>(xc, sbx, wt_ih0, mx0, ax0, kptr, 0);
        kt_mscale<<<dim3(RC * 3 / 4), blk, 0, stream>>>(mx0, ax0, uxn0, uxb0, b0, kptr);
        kt_scan2<<<dim3(B), dim3(512), 0, stream>>>(
            mx0, uxn0, uxb0, w1pk0, whh2g0, b0, hcar0, out0c, sbc, 256LL,
            mx0, uxn0, uxb0, w1pk0, whh2g0, b0, hcar0, out0c, sbc, 256LL,
            kptr, CT, B);
    }
    // ---- steady state: dual scans (L0 chunk c || L1 chunk c-1) ----
    for (int c = 1; c < NC; ++c) {
        const float* xc = x + (size_t)c * CT * 256;
        kt_gemm<<<dim3(12, RC / 64), blk, 0, stream>>>(xc, sbx, wt_ih0, mx0, ax0, kptr, 0);
        kt_mscale<<<dim3(RC * 3 / 4), blk, 0, stream>>>(mx0, ax0, uxn0, uxb0, b0, kptr);
        kt_gemm<<<dim3(12, RC / 64), blk, 0, stream>>>(out0c, sbc, wt_ih1, mx1, ax1, kptr, 1);
        kt_mscale<<<dim3(RC * 3 / 4), blk, 0, stream>>>(mx1, ax1, uxn1, uxb1, b1, kptr);
        kt_scan2<<<dim3(2 * B), dim3(512), 0, stream>>>(
            mx0, uxn0, uxb0, w1pk0, whh2g0, b0, hcar0, out0c, sbc, 256LL,
            mx1, uxn1, uxb1, w1pk1, whh2g1, b1, hcar1,
            out + (size_t)(c - 1) * CT * B * H, 256LL, (long long)B * H,
            kptr, CT, B);
    }
    // ---- epilogue: layer 1, chunk NC-1 ----
    {
        kt_gemm<<<dim3(12, RC / 64), blk, 0, stream>>>(out0c, sbc, wt_ih1, mx1, ax1, kptr, 1);
        kt_mscale<<<dim3(RC * 3 / 4), blk, 0, stream>>>(mx1, ax1, uxn1, uxb1, b1, kptr);
        kt_scan2<<<dim3(B), dim3(512), 0, stream>>>(
            mx1, uxn1, uxb1, w1pk1, whh2g1, b1, hcar1,
            out + (size_t)(NC - 1) * CT * B * H, 256LL, (long long)B * H,
            mx1, uxn1, uxb1, w1pk1, whh2g1, b1, hcar1,
            out + (size_t)(NC - 1) * CT * B * H, 256LL, (long long)B * H,
            kptr, CT, B);
    }
    kt_final<<<dim3(128), blk, 0, stream>>>(hcar, out + (size_t)T * B * H);
}

// Round 11
// 5367.406 us; speedup vs baseline: 2.4838x; 1.1428x over previous
//
#include <hip/hip_runtime.h>
#include <cstdint>
#include <cstddef>

#define MINN 1e-15f
#define EPSA 1e-7f
#define C_L2E 1.44269504088896341f
#define C_LN2 0.69314718055994531f

typedef _Float16 half_t;
typedef _Float16 half2_t __attribute__((ext_vector_type(2)));

#if defined(__has_builtin)
#if __has_builtin(__builtin_amdgcn_update_dpp) && __has_builtin(__builtin_amdgcn_readlane)
#define USE_DPP 1
#endif
#endif

// ---------- fast-math helpers (native, ~1 ulp) ----------
__device__ __forceinline__ float fexp2_(float x) {
#if defined(__has_builtin) && __has_builtin(__builtin_amdgcn_exp2f)
    return __builtin_amdgcn_exp2f(x);
#else
    return exp2f(x);
#endif
}
__device__ __forceinline__ float flog2_(float x) {
#if defined(__has_builtin) && __has_builtin(__builtin_amdgcn_logf)
    return __builtin_amdgcn_logf(x);
#else
    return log2f(x);
#endif
}
__device__ __forceinline__ float frcp_(float x) {
#if defined(__has_builtin) && __has_builtin(__builtin_amdgcn_rcpf)
    return __builtin_amdgcn_rcpf(x);
#else
    return 1.f / x;
#endif
}
__device__ __forceinline__ float tan_k_(float u, float sk, float rsk) {
    float a = fminf(fmaxf(sk * u, -15.f), 15.f);
    float t = fexp2_(a * (2.f * C_L2E));
    return (1.f - 2.f * frcp_(t + 1.f)) * rsk;
}
__device__ __forceinline__ float artan_k_(float u, float sk, float rsk) {
    float a = fminf(fmaxf(sk * u, -1.f + EPSA), 1.f - EPSA);
    return flog2_((1.f + a) * frcp_(1.f - a)) * (0.5f * C_LN2) * rsk;
}
__device__ __forceinline__ float sigm_(float x) {
    return frcp_(1.f + fexp2_(-x * C_L2E));
}
__device__ __forceinline__ float wave_sum(float v) {
#pragma unroll
    for (int off = 32; off; off >>= 1) v += __shfl_xor(v, off, 64);
    return v;
}

// ---------- DPP reduction primitives (VALU pipe, not DS) ----------
#ifdef USE_DPP
template <int CTRL, int RM, int BM>
__device__ __forceinline__ float dppmov_(float x) {
    return __builtin_bit_cast(float,
        __builtin_amdgcn_update_dpp(0, __builtin_bit_cast(int, x), CTRL, RM, BM, false));
}
#endif
// full 64-lane sum; result valid in lane 63 (fallback: all lanes)
__device__ __forceinline__ float wsum63_(float x) {
#ifdef USE_DPP
    x += dppmov_<0x111, 0xf, 0xf>(x);  // row_shr:1
    x += dppmov_<0x112, 0xf, 0xf>(x);  // row_shr:2
    x += dppmov_<0x114, 0xf, 0xe>(x);  // row_shr:4
    x += dppmov_<0x118, 0xf, 0xc>(x);  // row_shr:8
    x += dppmov_<0x142, 0xa, 0xf>(x);  // row_bcast:15
    x += dppmov_<0x143, 0xc, 0xf>(x);  // row_bcast:31 -> lane63 = total
    return x;
#else
    return wave_sum(x);
#endif
}
// 8-lane group sum; result valid in lane 8n+7 (fallback: all lanes)
__device__ __forceinline__ float gsum8_(float x) {
#ifdef USE_DPP
    x += dppmov_<0x111, 0xf, 0xf>(x);
    x += dppmov_<0x112, 0xf, 0xf>(x);
    x += dppmov_<0x114, 0xf, 0xe>(x);
    return x;
#else
    x += __shfl_xor(x, 1, 64);
    x += __shfl_xor(x, 2, 64);
    x += __shfl_xor(x, 4, 64);
    return x;
#endif
}
__device__ __forceinline__ float rdlane_(float x, int l) {
#ifdef USE_DPP
    return __builtin_bit_cast(float,
        __builtin_amdgcn_readlane(__builtin_bit_cast(int, x), l));
#else
    return __shfl(x, l, 64);
#endif
}
// block(512)-wide reduce of N values via DPP + 1 LDS round trip.
// ONE internal barrier; caller alternates redbuf between consecutive uses.
template <int N>
__device__ __forceinline__ void bredX(float* v, float* redbuf, int tid) {
    const int lane = tid & 63, wave = tid >> 6;
#pragma unroll
    for (int n = 0; n < N; ++n) {
        float s = wsum63_(v[n]);
        if (lane == 63) redbuf[n * 8 + wave] = s;
    }
    __syncthreads();
    float part = redbuf[lane & (8 * N - 1)];
    part = gsum8_(part);
#pragma unroll
    for (int n = 0; n < N; ++n) v[n] = rdlane_(part, 8 * n + 7);
}

// f16 pair dot-accumulate
__device__ __forceinline__ float dot2acc(uint32_t w, uint32_t h, float acc) {
#if defined(__has_builtin) && __has_builtin(__builtin_amdgcn_fdot2)
    return __builtin_amdgcn_fdot2(__builtin_bit_cast(half2_t, w),
                                  __builtin_bit_cast(half2_t, h), acc, false);
#else
    half2_t a = __builtin_bit_cast(half2_t, w);
    half2_t b = __builtin_bit_cast(half2_t, h);
    acc = fmaf((float)a[0], (float)b[0], acc);
    return fmaf((float)a[1], (float)b[1], acc);
#endif
}

// ---------- K1: transpose 2 ih weight matrices [768x256] -> [256x768] ----------
__global__ __launch_bounds__(256) void kt_transpose(
    const float* __restrict__ a0, const float* __restrict__ a1,
    float* __restrict__ o0, float* __restrict__ o1) {
    int idx = blockIdx.x * 256 + threadIdx.x;
    int m = idx / 196608, rem = idx % 196608;
    int j = rem >> 8, kk = rem & 255;
    const float* in = (m == 0) ? a0 : a1;
    float* outp     = (m == 0) ? o0 : o1;
    outp[kk * 768 + j] = in[j * 256 + kk];
}

// ---------- prep1: pack stage-1 (W_hr,W_hz) f16 per-thread fragments ----------
// HALF-WAVE pair layout: thread t: lane=t&63, wave=t>>6,
//   p = wave*32 + (lane&31), ph = lane>>5.
__global__ __launch_bounds__(256) void kt_prep1(
    const float* __restrict__ whh0, const float* __restrict__ whh1,
    uint32_t* __restrict__ p0, uint32_t* __restrict__ p1) {
    int idx = blockIdx.x * 256 + threadIdx.x;  // 131072
    int l = idx >> 16, e = idx & 65535;
    int r4 = e >> 11, rem = e & 2047;
    int t = rem >> 2, m = r4 * 4 + (rem & 3);
    int lane = t & 63, wave = t >> 6;
    int p = wave * 32 + (lane & 31), ph = lane >> 5;
    int g = m >> 6, mi = m & 63;
    int row = g ? (512 + p) : p;
    int i = ph * 128 + 2 * mi;
    const float* w = l ? whh1 : whh0;
    half2_t hv;
    hv[0] = (half_t)w[row * 256 + i];
    hv[1] = (half_t)w[row * 256 + i + 1];
    (l ? p1 : p0)[e] = __builtin_bit_cast(uint32_t, hv);
}

// ---------- prep2: pack stage-2 (W_hh_) f16 [i2][j] half2 ----------
__global__ __launch_bounds__(256) void kt_prep2(
    const float* __restrict__ whh0, const float* __restrict__ whh1,
    uint32_t* __restrict__ p0, uint32_t* __restrict__ p1) {
    int idx = blockIdx.x * 256 + threadIdx.x;  // 65536
    int l = idx >> 15, e = idx & 32767;
    int i2 = e >> 8, j = e & 255;
    const float* w = l ? whh1 : whh0;
    half2_t hv;
    hv[0] = (half_t)w[(256 + j) * 256 + 2 * i2];
    hv[1] = (half_t)w[(256 + j) * 256 + 2 * i2 + 1];
    (l ? p1 : p0)[e] = __builtin_bit_cast(uint32_t, hv);
}

// ---------- init / final ----------
__global__ __launch_bounds__(256) void kt_init(
    const float* __restrict__ h0, float* __restrict__ hcar) {
    int i = blockIdx.x * 256 + threadIdx.x;
    hcar[i] = h0[i];
}
__global__ __launch_bounds__(256) void kt_final(
    const float* __restrict__ hcar, float* __restrict__ dst) {
    int i = blockIdx.x * 256 + threadIdx.x;
    dst[i] = hcar[i];
}

// ================= MEGA KERNEL: scan roles + gemm roles =================
// CT = 32 fixed. Scan slot blocks: 64 each. Gemm slot blocks: 192 each
// (32 row-blocks of 64 rows x 6 col-blocks of 128).
struct MegaArgs {
    const float* s_mx[2]; const float* s_ax[2];
    const uint32_t* s_w1[2]; const uint32_t* s_whh[2];
    const float* s_bias[2]; float* s_hcar[2]; float* s_out[2];
    long long s_sb[2]; long long s_st[2];
    const float* g_A[2]; long long g_sB[2]; const float* g_Bt[2];
    float* g_C[2]; float* g_ax[2]; int g_mode[2];
    int nscan; int ngemm; int Tc;
    const float* kptr;
};

__global__ __launch_bounds__(512, 1) void kt_mega(MegaArgs a) {
    union Smem {
        struct {
            uint4 whhS[8192];       // 128 KiB W_hh_ f16
            uint32_t hy2S[128];
            uint32_t rh2S[128];
            float redbuf[2][64];
            float4 fS4[32];         // per (t): f_r, f_h, f_z
            float4 unS4[32];        // uxn_r, uxn_h, uxn_z
            float4 ubS4[32];        // uxb_r, uxb_h, uxb_z
        } s;
        struct {
            float As[16][68];
            float Bs[16][132];
            float sS[64];
        } g;
    };
    __shared__ Smem sm;
    const int tid = threadIdx.x;
    const int bid = blockIdx.x;
    const float k = a.kptr[0];
    const float sk = sqrtf(-k), rsk = frcp_(sk);
    const int Tc = a.Tc;  // 32

    if (bid >= a.nscan * 64) {
        // ==================== GEMM role ====================
        // C[rc][col] = s(rc) * sum_k A[rc][k] * Bt[k][col]; writes ax_out.
        int gb = bid - a.nscan * 64;
        int gs = gb / 192, w = gb % 192;
        const float* A = a.g_A[gs];
        const long long strideB = a.g_sB[gs];
        const float* Bt = a.g_Bt[gs];
        float* C = a.g_C[gs];
        float* axo = a.g_ax[gs];
        const int mode = a.g_mode[gs];
        int rb = w / 6, cb = w % 6;
        int row0 = rb * 64, col0 = cb * 128;

        // fused rowscale: 8 lanes per row, 32 elems each
        {
            int row = tid >> 3, oct = tid & 7;
            int rc = row0 + row;
            size_t base = (size_t)(rc >> 5) * strideB + (size_t)(rc & 31) * 256 + oct * 32;
            float n2 = 0.f;
#pragma unroll
            for (int u = 0; u < 8; ++u) {
                float4 v = *(const float4*)&A[base + u * 4];
                n2 += v.x * v.x + v.y * v.y + v.z * v.z + v.w * v.w;
            }
            n2 += __shfl_xor(n2, 1, 64);
            n2 += __shfl_xor(n2, 2, 64);
            n2 += __shfl_xor(n2, 4, 64);
            float n = sqrtf(n2);
            float s, xn;
            if (mode == 0) {
                float nrm = fmaxf(n, MINN);
                float tk = tan_k_(nrm, sk, rsk);
                s = tk * frcp_(nrm);
                xn = fmaxf(tk * (n * frcp_(nrm)), MINN);
            } else {
                s = 1.f;
                xn = fmaxf(n, MINN);
            }
            float ax = artan_k_(xn, sk, rsk) * frcp_(xn);
            if (oct == 0) { sm.g.sS[row] = s; if (cb == 0) axo[rc] = ax; }
        }
        __syncthreads();

        int ty = tid >> 5, tx = tid & 31;  // 16 row-quads x 32 col-quads
        float acc[4][4] = {};
#pragma unroll 1
        for (int kt = 0; kt < 16; ++kt) {
            int k0 = kt * 16;
            if (tid < 256) {
                int ra = tid >> 2, kq = tid & 3;
                int rc = row0 + ra;
                size_t aoff = (size_t)(rc >> 5) * strideB + (size_t)(rc & 31) * 256 + k0 + kq * 4;
                float4 av = *(const float4*)&A[aoff];
                float sc = sm.g.sS[ra];
                sm.g.As[kq * 4 + 0][ra] = av.x * sc;
                sm.g.As[kq * 4 + 1][ra] = av.y * sc;
                sm.g.As[kq * 4 + 2][ra] = av.z * sc;
                sm.g.As[kq * 4 + 3][ra] = av.w * sc;
            }
            {
                int kb = tid >> 5, cq = tid & 31;
                float4 bv = *(const float4*)&Bt[(size_t)(k0 + kb) * 768 + col0 + cq * 4];
                *(float4*)&sm.g.Bs[kb][cq * 4] = bv;
            }
            __syncthreads();
#pragma unroll
            for (int kk = 0; kk < 16; ++kk) {
                float4 a4 = *(const float4*)&sm.g.As[kk][ty * 4];
                float4 b4 = *(const float4*)&sm.g.Bs[kk][tx * 4];
                float aa[4] = {a4.x, a4.y, a4.z, a4.w};
                float bb[4] = {b4.x, b4.y, b4.z, b4.w};
#pragma unroll
                for (int i = 0; i < 4; ++i)
#pragma unroll
                    for (int j = 0; j < 4; ++j)
                        acc[i][j] = fmaf(aa[i], bb[j], acc[i][j]);
            }
            __syncthreads();
        }
#pragma unroll
        for (int i = 0; i < 4; ++i) {
            size_t row = (size_t)row0 + ty * 4 + i;
            *(float4*)&C[row * 768 + col0 + tx * 4] =
                make_float4(acc[i][0], acc[i][1], acc[i][2], acc[i][3]);
        }
        return;
    }

    // ==================== SCAN role ====================
    const int slot = bid >> 6, bb = bid & 63;
    const float* mx      = a.s_mx[slot];
    const float* axp     = a.s_ax[slot];
    const uint32_t* w1pk = a.s_w1[slot];
    const uint32_t* whh2g= a.s_whh[slot];
    const float* bias    = a.s_bias[slot];
    float* hcar          = a.s_hcar[slot];
    float* outbase       = a.s_out[slot];
    const long long stride_b = a.s_sb[slot];
    const long long stride_t = a.s_st[slot];

    const int lane = tid & 63, wave = tid >> 6;
    const int p = wave * 32 + (lane & 31), ph = lane >> 5;

    // stage-2 weights -> LDS
    for (int idx = tid; idx < 32768; idx += 512) {
        uint32_t v = whh2g[idx];
        int i2 = idx >> 8, col = idx & 255;
        ((uint32_t*)sm.s.whhS)[((i2 >> 2) * 256 + col) * 4 + (i2 & 3)] = v;
    }
    // stage-1 weights -> registers (128 u32 = 256 f16)
    uint32_t w1[128];
    {
        const uint4* wp = (const uint4*)w1pk;  // [32][512] uint4
#pragma unroll
        for (int r4 = 0; r4 < 32; ++r4) {
            uint4 v = wp[r4 * 512 + tid];
            w1[4 * r4 + 0] = v.x; w1[4 * r4 + 1] = v.y;
            w1[4 * r4 + 2] = v.z; w1[4 * r4 + 3] = v.w;
        }
    }

    const float* uxpb = mx + (size_t)bb * Tc * 768;

    // ---- inline mscale prologue: per (t,g): f, uxn, uxb into LDS ----
    {
        const int UPW = (Tc * 3) >> 3;  // 12 units per wave
#pragma unroll 1
        for (int i = 0; i < UPW; ++i) {
            int u = wave * UPW + i;
            int tt = u / 3, g = u - 3 * tt;
            const float* rowp = uxpb + (size_t)tt * 768 + g * 256 + lane * 4;
            float4 v = *(const float4*)rowp;
            float4 b4 = *(const float4*)&bias[g * 256 + lane * 4];
            float n2 = wsum63_(v.x * v.x + v.y * v.y + v.z * v.z + v.w * v.w);
            float vb = wsum63_(v.x * b4.x + v.y * b4.y + v.z * b4.z + v.w * b4.w);
            if (lane == 63) {
                float nt = sqrtf(n2);
                float mxn = fmaxf(nt, MINN);
                float arg = mxn * axp[bb * Tc + tt];
                float tk = tan_k_(arg, sk, rsk);
                float f = tk * frcp_(mxn);
                ((float*)&sm.s.fS4[tt])[g] = f;
                ((float*)&sm.s.unS4[tt])[g] = tk * (nt * frcp_(mxn));
                ((float*)&sm.s.ubS4[tt])[g] = f * vb;
            }
        }
    }

    const float br = bias[p], bh = bias[256 + p], bz = bias[512 + p];
    float h = hcar[bb * 256 + p];
    __syncthreads();  // whhS + fS/un/ub ready
    float v4[4] = {br * br, bh * bh, bz * bz, h * h};
    bredX<4>(v4, sm.s.redbuf[0], tid);
    const float bn2r = 0.5f * v4[0], bn2h = 0.5f * v4[1], bn2z = 0.5f * v4[2];
    float S_h2 = 0.5f * v4[3];

    float* myout = outbase + (size_t)bb * stride_b;

    // prefetch step 0 raw ux
    float prawr = uxpb[p], prawh = uxpb[256 + p], prawz = uxpb[512 + p];

    for (int t = 0; t < Tc; ++t) {
        const float4 ff = sm.s.fS4[t];
        const float4 uu = sm.s.unS4[t];
        const float4 ub = sm.s.ubS4[t];
        const float uxr = prawr * ff.x, uxh = prawh * ff.y, uxz = prawz * ff.z;
        const float unr = uu.x, unh = uu.y, unz = uu.z;
        const float S_ubr = ub.x, S_ubh = ub.y, S_ubz = ub.z;

        // ---- expmap0(h): scalars from carried S_h2 ----
        float hn = sqrtf(S_h2);
        float nrm = fmaxf(hn, MINN);
        float tk0 = tan_k_(nrm, sk, rsk);
        float chy = tk0 * frcp_(nrm);
        float hy = chy * h;
        float Shy2 = chy * chy * S_h2;
        float xnh = fmaxf(tk0 * (hn * frcp_(nrm)), MINN);
        float axh = artan_k_(xnh, sk, rsk) * frcp_(xnh);
        if (ph == 0) ((half_t*)sm.s.hy2S)[p] = (half_t)hy;
        __syncthreads();  // B1: hy ready

        // prefetch next step raw ux (hidden under matvec + reductions)
        if (t + 1 < Tc) {
            const float* uxp2 = uxpb + (size_t)(t + 1) * 768;
            prawr = uxp2[p]; prawh = uxp2[256 + p]; prawz = uxp2[512 + p];
        }

        // ---- stage-1 matvec (r,z), half-split, 4-deep accumulators ----
        float prA[4] = {0.f, 0.f, 0.f, 0.f};
        float pzA[4] = {0.f, 0.f, 0.f, 0.f};
        {
            const uint4* hp = (const uint4*)sm.s.hy2S + ph * 16;
#pragma unroll
            for (int c4 = 0; c4 < 4; ++c4) {
                uint32_t hv[16];
#pragma unroll
                for (int u = 0; u < 4; ++u) {
                    uint4 v = hp[c4 * 4 + u];
                    hv[4 * u + 0] = v.x; hv[4 * u + 1] = v.y;
                    hv[4 * u + 2] = v.z; hv[4 * u + 3] = v.w;
                }
#pragma unroll
                for (int m = 0; m < 16; ++m) {
                    prA[c4] = dot2acc(w1[c4 * 16 + m], hv[m], prA[c4]);
                    pzA[c4] = dot2acc(w1[64 + c4 * 16 + m], hv[m], pzA[c4]);
                }
            }
        }
        float pr = (prA[0] + prA[1]) + (prA[2] + prA[3]);
        float pz = (pzA[0] + pzA[1]) + (pzA[2] + pzA[3]);
        const float mr = pr + __shfl_xor(pr, 32, 64);
        const float mz = pz + __shfl_xor(pz, 32, 64);

        float vr[8] = {mr * mr, mz * mz, mr * uxr, mz * uxz,
                       mr * br, mz * bz, h * uxh, h * bh};
        bredX<8>(vr, sm.s.redbuf[0], tid);
        const float S_mr2 = 0.5f * vr[0], S_mz2 = 0.5f * vr[1];
        const float S_mru = 0.5f * vr[2], S_mzu = 0.5f * vr[3];
        const float S_mrb = 0.5f * vr[4], S_mzb = 0.5f * vr[5];
        const float S_huxh = 0.5f * vr[6], S_hbh = 0.5f * vr[7];

        // ---- gates r,z: ONE chain per lane; ph=0 -> r, ph=1 -> z ----
        const float m_   = ph ? mz    : mr;
        const float S2_  = ph ? S_mz2 : S_mr2;
        const float Su_  = ph ? S_mzu : S_mru;
        const float Sb_  = ph ? S_mzb : S_mrb;
        const float Sub_ = ph ? S_ubz : S_ubr;
        const float bn2_ = ph ? bn2z  : bn2r;
        const float un_  = ph ? unz   : unr;
        const float ux_  = ph ? uxz   : uxr;
        const float b_   = ph ? bz    : br;
        float g_own;
        {
            float mxn = fmaxf(sqrtf(S2_), MINN);
            float tk = tan_k_(mxn * axh, sk, rsk);
            float f = tk * frcp_(mxn);
            float x2 = f * f * S2_, y2 = un_ * un_, xy = f * Su_;
            float aq = 1.f - 2.f * k * xy - k * y2;
            float bq = 1.f + k * x2;
            float rd = frcp_(fmaxf(1.f - 2.f * k * xy + k * k * x2 * y2, MINN));
            float c1 = (aq * f * m_ + bq * ux_) * rd;
            float Sc12 = (aq * aq * x2 + 2.f * aq * bq * xy + bq * bq * y2) * (rd * rd);
            float Sc1b = (aq * f * Sb_ + bq * Sub_) * rd;
            float g = 1.f - 2.f * k * Sc1b - k * bn2_;
            float dl = 1.f + k * Sc12;
            float re = frcp_(fmaxf(1.f - 2.f * k * Sc1b + k * k * Sc12 * bn2_, MINN));
            float c2 = (g * c1 + dl * b_) * re;
            float Sc22 = (g * g * Sc12 + 2.f * g * dl * Sc1b + dl * dl * bn2_) * (re * re);
            float yn = fmaxf(sqrtf(Sc22), MINN);
            float lg = artan_k_(yn, sk, rsk) * frcp_(yn) * c2;
            g_own = sigm_(lg);
        }
        const float g_oth = __shfl_xor(g_own, 32, 64);
        const float r_t = ph ? g_oth : g_own;
        const float z_t = ph ? g_own : g_oth;

        // ---- rh: publish UNSCALED wx; merge S_wx2 reduction into same barrier ----
        float wx = r_t * hy;
        if (ph == 0) ((half_t*)sm.s.rh2S)[p] = (half_t)wx;
        {
            float s1v = wsum63_(wx * wx);
            if (lane == 63) sm.s.redbuf[1][wave] = s1v;
        }
        __syncthreads();  // B_B: rh/wx ready + partials ready

        float part1 = gsum8_(sm.s.redbuf[1][lane & 7]);
        const float S_wx2 = 0.5f * rdlane_(part1, 7);
        float wxt = sqrtf(S_wx2);
        float wxn = fmaxf(wxt, MINN);
        float tkw = tan_k_(wxn * axh, sk, rsk);
        float fw = tkw * frcp_(wxn);      // rh = fw * wx (fw block scalar)
        float rhn = tkw * (wxt * frcp_(wxn));

        // ---- stage-2 matvec (h gate), half-split, 4-deep accumulators ----
        float qA[4] = {0.f, 0.f, 0.f, 0.f};
        {
            const uint4* rp = (const uint4*)sm.s.rh2S + ph * 16;
#pragma unroll
            for (int u = 0; u < 16; ++u) {
                uint4 wv = sm.s.whhS[(ph * 16 + u) * 256 + p];
                uint4 rv = rp[u];
                int s = u >> 2;
                qA[s] = dot2acc(wv.x, rv.x, qA[s]);
                qA[s] = dot2acc(wv.y, rv.y, qA[s]);
                qA[s] = dot2acc(wv.z, rv.z, qA[s]);
                qA[s] = dot2acc(wv.w, rv.w, qA[s]);
            }
        }
        float qq = (qA[0] + qA[1]) + (qA[2] + qA[3]);
        const float mh = fw * (qq + __shfl_xor(qq, 32, 64));

        float v4b[4] = {mh * mh, mh * uxh, mh * bh, hy * mh};
        bredX<4>(v4b, sm.s.redbuf[0], tid);
        const float S_mh2 = 0.5f * v4b[0], S_mhu = 0.5f * v4b[1];
        const float S_mhb = 0.5f * v4b[2], S_hymh = 0.5f * v4b[3];

        float wz, Sdelta2;
        {
            float xnrh = fmaxf(rhn, MINN);
            float axrh = artan_k_(xnrh, sk, rsk) * frcp_(xnrh);
            float mxn = fmaxf(sqrtf(S_mh2), MINN);
            float tk = tan_k_(mxn * axrh, sk, rsk);
            float f = tk * frcp_(mxn);
            float x2 = f * f * S_mh2, y2 = unh * unh, xy = f * S_mhu;
            float aq = 1.f - 2.f * k * xy - k * y2;
            float bq = 1.f + k * x2;
            float rd = frcp_(fmaxf(1.f - 2.f * k * xy + k * k * x2 * y2, MINN));
            float c1 = (aq * f * mh + bq * uxh) * rd;
            float Sc12 = (aq * aq * x2 + 2.f * aq * bq * xy + bq * bq * y2) * (rd * rd);
            float Sc1b = (aq * f * S_mhb + bq * S_ubh) * rd;
            float S_hyc1 = (aq * f * S_hymh + bq * chy * S_huxh) * rd;
            float g = 1.f - 2.f * k * Sc1b - k * bn2h;
            float dl = 1.f + k * Sc12;
            float re = frcp_(fmaxf(1.f - 2.f * k * Sc1b + k * k * Sc12 * bn2h, MINN));
            float htl = (g * c1 + dl * bh) * re;
            float Shtl2 = (g * g * Sc12 + 2.f * g * dl * Sc1b + dl * dl * bn2h) * (re * re);
            float S_hyhtl = (g * S_hyc1 + dl * chy * S_hbh) * re;
            // delta = mobius_add(-hy, htl): xy_d = -S_hyhtl
            float ad = 1.f + 2.f * k * S_hyhtl - k * Shtl2;
            float bd = 1.f + k * Shy2;
            float rdd = frcp_(fmaxf(1.f + 2.f * k * S_hyhtl + k * k * Shy2 * Shtl2, MINN));
            float delta = (ad * (-hy) + bd * htl) * rdd;
            Sdelta2 = (ad * ad * Shy2 - 2.f * ad * bd * S_hyhtl + bd * bd * Shtl2) * (rdd * rdd);
            wz = z_t * delta;
        }
        float v2[2] = {wz * wz, hy * wz};
        bredX<2>(v2, sm.s.redbuf[1], tid);
        const float S_wz2 = 0.5f * v2[0], S_hywz = 0.5f * v2[1];

        {
            float dnc = fmaxf(sqrtf(Sdelta2), MINN);
            float axd = artan_k_(dnc, sk, rsk) * frcp_(dnc);
            float wzt = sqrtf(S_wz2);
            float wznc = fmaxf(wzt, MINN);
            float tkzd = tan_k_(wznc * axd, sk, rsk);
            float fz = tkzd * frcp_(wznc);
            float zd = fz * wz;
            float zdn2 = fz * fz * S_wz2;
            float S_hyzd = fz * S_hywz;
            float an = 1.f - 2.f * k * S_hyzd - k * zdn2;
            float bn_ = 1.f + k * Shy2;
            float rdn = frcp_(fmaxf(1.f - 2.f * k * S_hyzd + k * k * Shy2 * zdn2, MINN));
            float hnew = (an * hy + bn_ * zd) * rdn;
            float Shnew2 = (an * an * Shy2 + 2.f * an * bn_ * S_hyzd + bn_ * bn_ * zdn2) * (rdn * rdn);
            float yn = fmaxf(sqrtf(Shnew2), MINN);
            float ayn = artan_k_(yn, sk, rsk) * frcp_(yn);
            float outv = ayn * hnew;
            if (ph == 0) myout[(size_t)t * stride_t + p] = outv;
            h = outv;
            S_h2 = ayn * ayn * Shnew2;  // carried
        }
    }
    if (ph == 0) hcar[bb * 256 + p] = h;
}

// ---------- host launcher ----------
extern "C" void kernel_launch(void* const* d_in, const int* in_sizes, int n_in,
                              void* d_out, int out_size, void* d_ws, size_t ws_size,
                              hipStream_t stream) {
    const float* x    = (const float*)d_in[0];
    const float* kptr = (const float*)d_in[1];
    const float* h0   = (const float*)d_in[2];
    const float* wih0 = (const float*)d_in[3];
    const float* whh0 = (const float*)d_in[4];
    const float* b0   = (const float*)d_in[5];
    const float* wih1 = (const float*)d_in[6];
    const float* whh1 = (const float*)d_in[7];
    const float* b1   = (const float*)d_in[8];
    float* out = (float*)d_out;
    float* ws  = (float*)d_ws;

    const int B = 64, T = 1024, H = 256;
    const int CT = 32, NC = 32;
    const int RC = B * CT;        // 2048 chunk rows
    const int GBLK = (RC / 64) * 6;  // 192 gemm blocks per slot

    // ws layout (float slots), total 7,970,816 floats (~30.4 MiB)
    float* wt_ih0 = ws;
    float* wt_ih1 = wt_ih0 + 196608;
    uint32_t* w1pk0  = (uint32_t*)(wt_ih1 + 196608);
    uint32_t* w1pk1  = w1pk0 + 65536;
    uint32_t* whh2g0 = w1pk1 + 65536;
    uint32_t* whh2g1 = whh2g0 + 32768;
    float* hcar  = (float*)(whh2g1 + 32768);      // 32768
    float* ax0b_[2], *ax1b_[2], *out0c_[2], *mx0_[2], *mx1_[2];
    {
        float* cur = hcar + 32768;
        ax0b_[0] = cur; cur += RC;
        ax0b_[1] = cur; cur += RC;
        ax1b_[0] = cur; cur += RC;
        ax1b_[1] = cur; cur += RC;
        out0c_[0] = cur; cur += (size_t)RC * H;
        out0c_[1] = cur; cur += (size_t)RC * H;
        mx0_[0] = cur; cur += (size_t)RC * 768;
        mx0_[1] = cur; cur += (size_t)RC * 768;
        mx1_[0] = cur; cur += (size_t)RC * 768;
        mx1_[1] = cur; cur += (size_t)RC * 768;
    }
    float* hcar0 = hcar;
    float* hcar1 = hcar + (size_t)B * H;

    dim3 blk(256);
    kt_transpose<<<dim3(1536), blk, 0, stream>>>(wih0, wih1, wt_ih0, wt_ih1);
    kt_prep1<<<dim3(512), blk, 0, stream>>>(whh0, whh1, w1pk0, w1pk1);
    kt_prep2<<<dim3(256), blk, 0, stream>>>(whh0, whh1, whh2g0, whh2g1);
    kt_init<<<dim3(128), blk, 0, stream>>>(h0, hcar);

    // pre-launch: gemm L0 chunk 0 only
    {
        MegaArgs a{};
        a.nscan = 0; a.ngemm = 1; a.Tc = CT; a.kptr = kptr;
        a.g_A[0] = x; a.g_sB[0] = (long long)T * 256; a.g_Bt[0] = wt_ih0;
        a.g_C[0] = mx0_[0]; a.g_ax[0] = ax0b_[0]; a.g_mode[0] = 0;
        kt_mega<<<dim3(GBLK), dim3(512), 0, stream>>>(a);
    }

    for (int c = 0; c <= NC + 1; ++c) {
        MegaArgs a{};
        int ns = 0, ng = 0;
        if (c <= NC - 1) {  // scan L0 chunk c
            a.s_mx[ns] = mx0_[c & 1]; a.s_ax[ns] = ax0b_[c & 1];
            a.s_w1[ns] = w1pk0; a.s_whh[ns] = whh2g0;
            a.s_bias[ns] = b0; a.s_hcar[ns] = hcar0;
            a.s_out[ns] = out0c_[c & 1];
            a.s_sb[ns] = (long long)CT * 256; a.s_st[ns] = 256;
            ns++;
        }
        int d = c - 2;
        if (d >= 0 && d <= NC - 1) {  // scan L1 chunk d
            a.s_mx[ns] = mx1_[d & 1]; a.s_ax[ns] = ax1b_[d & 1];
            a.s_w1[ns] = w1pk1; a.s_whh[ns] = whh2g1;
            a.s_bias[ns] = b1; a.s_hcar[ns] = hcar1;
            a.s_out[ns] = out + (size_t)d * CT * B * H;
            a.s_sb[ns] = 256; a.s_st[ns] = (long long)B * H;
            ns++;
        }
        int e = c + 1;
        if (e <= NC - 1) {  // gemm L0 chunk e
            a.g_A[ng] = x + (size_t)e * CT * 256; a.g_sB[ng] = (long long)T * 256;
            a.g_Bt[ng] = wt_ih0; a.g_C[ng] = mx0_[e & 1];
            a.g_ax[ng] = ax0b_[e & 1]; a.g_mode[ng] = 0;
            ng++;
        }
        int f = c - 1;
        if (f >= 0 && f <= NC - 1) {  // gemm L1 chunk f
            a.g_A[ng] = out0c_[f & 1]; a.g_sB[ng] = (long long)CT * 256;
            a.g_Bt[ng] = wt_ih1; a.g_C[ng] = mx1_[f & 1];
            a.g_ax[ng] = ax1b_[f & 1]; a.g_mode[ng] = 1;
            ng++;
        }
        a.nscan = ns; a.ngemm = ng; a.Tc = CT; a.kptr = kptr;
        int nb = ns * 64 + ng * GBLK;
        if (nb > 0)
            kt_mega<<<dim3(nb), dim3(512), 0, stream>>>(a);
    }
    kt_final<<<dim3(128), blk, 0, stream>>>(hcar, out + (size_t)T * B * H);
}

// Round 13
// 5299.320 us; speedup vs baseline: 2.5157x; 1.0128x over previous
//
#include <hip/hip_runtime.h>
#include <cstdint>
#include <cstddef>

#define MINN 1e-15f
#define EPSA 1e-7f
#define C_L2E 1.44269504088896341f
#define C_LN2 0.69314718055994531f

typedef _Float16 half_t;
typedef _Float16 half2_t __attribute__((ext_vector_type(2)));

#if defined(__has_builtin)
#if __has_builtin(__builtin_amdgcn_update_dpp) && __has_builtin(__builtin_amdgcn_readlane)
#define USE_DPP 1
#endif
#endif

// ---------- fast-math helpers (native, ~1 ulp) ----------
__device__ __forceinline__ float fexp2_(float x) {
#if defined(__has_builtin) && __has_builtin(__builtin_amdgcn_exp2f)
    return __builtin_amdgcn_exp2f(x);
#else
    return exp2f(x);
#endif
}
__device__ __forceinline__ float flog2_(float x) {
#if defined(__has_builtin) && __has_builtin(__builtin_amdgcn_logf)
    return __builtin_amdgcn_logf(x);
#else
    return log2f(x);
#endif
}
__device__ __forceinline__ float frcp_(float x) {
#if defined(__has_builtin) && __has_builtin(__builtin_amdgcn_rcpf)
    return __builtin_amdgcn_rcpf(x);
#else
    return 1.f / x;
#endif
}
__device__ __forceinline__ float tan_k_(float u, float sk, float rsk) {
    float a = fminf(fmaxf(sk * u, -15.f), 15.f);
    float t = fexp2_(a * (2.f * C_L2E));
    return (1.f - 2.f * frcp_(t + 1.f)) * rsk;
}
__device__ __forceinline__ float artan_k_(float u, float sk, float rsk) {
    float a = fminf(fmaxf(sk * u, -1.f + EPSA), 1.f - EPSA);
    return flog2_((1.f + a) * frcp_(1.f - a)) * (0.5f * C_LN2) * rsk;
}
__device__ __forceinline__ float sigm_(float x) {
    return frcp_(1.f + fexp2_(-x * C_L2E));
}
__device__ __forceinline__ float wave_sum(float v) {
#pragma unroll
    for (int off = 32; off; off >>= 1) v += __shfl_xor(v, off, 64);
    return v;
}

// ---------- DPP reduction primitives (VALU pipe, not DS) ----------
#ifdef USE_DPP
template <int CTRL, int RM, int BM>
__device__ __forceinline__ float dppmov_(float x) {
    return __builtin_bit_cast(float,
        __builtin_amdgcn_update_dpp(0, __builtin_bit_cast(int, x), CTRL, RM, BM, false));
}
#endif
// full 64-lane sum; result valid in lane 63 (fallback: all lanes)
__device__ __forceinline__ float wsum63_(float x) {
#ifdef USE_DPP
    x += dppmov_<0x111, 0xf, 0xf>(x);  // row_shr:1
    x += dppmov_<0x112, 0xf, 0xf>(x);  // row_shr:2
    x += dppmov_<0x114, 0xf, 0xe>(x);  // row_shr:4
    x += dppmov_<0x118, 0xf, 0xc>(x);  // row_shr:8
    x += dppmov_<0x142, 0xa, 0xf>(x);  // row_bcast:15
    x += dppmov_<0x143, 0xc, 0xf>(x);  // row_bcast:31 -> lane63 = total
    return x;
#else
    return wave_sum(x);
#endif
}
// 8-lane group sum; result valid in lane 8n+7 (fallback: all lanes)
__device__ __forceinline__ float gsum8_(float x) {
#ifdef USE_DPP
    x += dppmov_<0x111, 0xf, 0xf>(x);
    x += dppmov_<0x112, 0xf, 0xf>(x);
    x += dppmov_<0x114, 0xf, 0xe>(x);
    return x;
#else
    x += __shfl_xor(x, 1, 64);
    x += __shfl_xor(x, 2, 64);
    x += __shfl_xor(x, 4, 64);
    return x;
#endif
}
__device__ __forceinline__ float rdlane_(float x, int l) {
#ifdef USE_DPP
    return __builtin_bit_cast(float,
        __builtin_amdgcn_readlane(__builtin_bit_cast(int, x), l));
#else
    return __shfl(x, l, 64);
#endif
}
// block(512)-wide reduce of N values via DPP + 1 LDS round trip.
// ONE internal barrier; caller alternates redbuf between consecutive uses.
template <int N>
__device__ __forceinline__ void bredX(float* v, float* redbuf, int tid) {
    const int lane = tid & 63, wave = tid >> 6;
#pragma unroll
    for (int n = 0; n < N; ++n) {
        float s = wsum63_(v[n]);
        if (lane == 63) redbuf[n * 8 + wave] = s;
    }
    __syncthreads();
    float part = redbuf[lane & (8 * N - 1)];
    part = gsum8_(part);
#pragma unroll
    for (int n = 0; n < N; ++n) v[n] = rdlane_(part, 8 * n + 7);
}

// f16 pair dot-accumulate
__device__ __forceinline__ float dot2acc(uint32_t w, uint32_t h, float acc) {
#if defined(__has_builtin) && __has_builtin(__builtin_amdgcn_fdot2)
    return __builtin_amdgcn_fdot2(__builtin_bit_cast(half2_t, w),
                                  __builtin_bit_cast(half2_t, h), acc, false);
#else
    half2_t a = __builtin_bit_cast(half2_t, w);
    half2_t b = __builtin_bit_cast(half2_t, h);
    acc = fmaf((float)a[0], (float)b[0], acc);
    return fmaf((float)a[1], (float)b[1], acc);
#endif
}

// ---------- K1: transpose 2 ih weight matrices [768x256] -> [256x768] ----------
__global__ __launch_bounds__(256) void kt_transpose(
    const float* __restrict__ a0, const float* __restrict__ a1,
    float* __restrict__ o0, float* __restrict__ o1) {
    int idx = blockIdx.x * 256 + threadIdx.x;
    int m = idx / 196608, rem = idx % 196608;
    int j = rem >> 8, kk = rem & 255;
    const float* in = (m == 0) ? a0 : a1;
    float* outp     = (m == 0) ? o0 : o1;
    outp[kk * 768 + j] = in[j * 256 + kk];
}

// ---------- prep1: pack stage-1 (W_hr,W_hz) f16 per-thread fragments ----------
// HALF-WAVE pair layout: thread t: lane=t&63, wave=t>>6,
//   p = wave*32 + (lane&31), ph = lane>>5.
__global__ __launch_bounds__(256) void kt_prep1(
    const float* __restrict__ whh0, const float* __restrict__ whh1,
    uint32_t* __restrict__ p0, uint32_t* __restrict__ p1) {
    int idx = blockIdx.x * 256 + threadIdx.x;  // 131072
    int l = idx >> 16, e = idx & 65535;
    int r4 = e >> 11, rem = e & 2047;
    int t = rem >> 2, m = r4 * 4 + (rem & 3);
    int lane = t & 63, wave = t >> 6;
    int p = wave * 32 + (lane & 31), ph = lane >> 5;
    int g = m >> 6, mi = m & 63;
    int row = g ? (512 + p) : p;
    int i = ph * 128 + 2 * mi;
    const float* w = l ? whh1 : whh0;
    half2_t hv;
    hv[0] = (half_t)w[row * 256 + i];
    hv[1] = (half_t)w[row * 256 + i + 1];
    (l ? p1 : p0)[e] = __builtin_bit_cast(uint32_t, hv);
}

// ---------- prep2: pack stage-2 (W_hh_) f16 in FINAL LDS order ----------
// dst u32 index = ((i2>>2)*256 + j)*4 + (i2&3) so the scan stages with
// linear uint4 copies (16B loads + ds_write_b128).
__global__ __launch_bounds__(256) void kt_prep2(
    const float* __restrict__ whh0, const float* __restrict__ whh1,
    uint32_t* __restrict__ p0, uint32_t* __restrict__ p1) {
    int idx = blockIdx.x * 256 + threadIdx.x;  // 65536
    int l = idx >> 15, e = idx & 32767;
    int i2 = e >> 8, j = e & 255;
    const float* w = l ? whh1 : whh0;
    half2_t hv;
    hv[0] = (half_t)w[(256 + j) * 256 + 2 * i2];
    hv[1] = (half_t)w[(256 + j) * 256 + 2 * i2 + 1];
    int dst = ((i2 >> 2) * 256 + j) * 4 + (i2 & 3);
    (l ? p1 : p0)[dst] = __builtin_bit_cast(uint32_t, hv);
}

// ---------- init / final ----------
__global__ __launch_bounds__(256) void kt_init(
    const float* __restrict__ h0, float* __restrict__ hcar) {
    int i = blockIdx.x * 256 + threadIdx.x;
    hcar[i] = h0[i];
}
__global__ __launch_bounds__(256) void kt_final(
    const float* __restrict__ hcar, float* __restrict__ dst) {
    int i = blockIdx.x * 256 + threadIdx.x;
    dst[i] = hcar[i];
}

// ================= MEGA KERNEL: scan roles + gemm roles =================
// CT = 32 fixed. Scan slot blocks: 64 each. Gemm slot blocks: 192 each
// (32 row-blocks of 64 rows x 6 col-blocks of 128).
struct MegaArgs {
    const float* s_mx[2]; const float* s_ax[2];
    const uint32_t* s_w1[2]; const uint32_t* s_whh[2];
    const float* s_bias[2]; float* s_hcar[2]; float* s_out[2];
    long long s_sb[2]; long long s_st[2];
    const float* g_A[2]; long long g_sB[2]; const float* g_Bt[2];
    float* g_C[2]; float* g_ax[2]; int g_mode[2];
    int nscan; int ngemm; int Tc;
    const float* kptr;
};

__global__ __launch_bounds__(512, 1) void kt_mega(MegaArgs a) {
    union Smem {
        struct {
            uint4 whhS[8192];       // 128 KiB W_hh_ f16
            uint32_t hy2S[128];
            uint32_t rh2S[128];
            float redbuf[2][64];
            float4 fS4[32];         // per (t): f_r, f_h, f_z
            float4 unS4[32];        // uxn_r, uxn_h, uxn_z
            float4 ubS4[32];        // uxb_r, uxb_h, uxb_z
        } s;
        struct {
            float As[16][68];
            float Bs[16][132];
            float sS[64];
        } g;
    };
    __shared__ Smem sm;
    const int tid = threadIdx.x;
    const int bid = blockIdx.x;
    const float k = a.kptr[0];
    const float sk = sqrtf(-k), rsk = frcp_(sk);
    const int Tc = a.Tc;  // 32

    if (bid >= a.nscan * 64) {
        // ==================== GEMM role ====================
        int gb = bid - a.nscan * 64;
        int gs = gb / 192, w = gb % 192;
        const float* A = a.g_A[gs];
        const long long strideB = a.g_sB[gs];
        const float* Bt = a.g_Bt[gs];
        float* C = a.g_C[gs];
        float* axo = a.g_ax[gs];
        const int mode = a.g_mode[gs];
        int rb = w / 6, cb = w % 6;
        int row0 = rb * 64, col0 = cb * 128;

        // fused rowscale: 8 lanes per row, 32 elems each
        {
            int row = tid >> 3, oct = tid & 7;
            int rc = row0 + row;
            size_t base = (size_t)(rc >> 5) * strideB + (size_t)(rc & 31) * 256 + oct * 32;
            float n2 = 0.f;
#pragma unroll
            for (int u = 0; u < 8; ++u) {
                float4 v = *(const float4*)&A[base + u * 4];
                n2 += v.x * v.x + v.y * v.y + v.z * v.z + v.w * v.w;
            }
            n2 += __shfl_xor(n2, 1, 64);
            n2 += __shfl_xor(n2, 2, 64);
            n2 += __shfl_xor(n2, 4, 64);
            float n = sqrtf(n2);
            float s, xn;
            if (mode == 0) {
                float nrm = fmaxf(n, MINN);
                float tk = tan_k_(nrm, sk, rsk);
                s = tk * frcp_(nrm);
                xn = fmaxf(tk * (n * frcp_(nrm)), MINN);
            } else {
                s = 1.f;
                xn = fmaxf(n, MINN);
            }
            float ax = artan_k_(xn, sk, rsk) * frcp_(xn);
            if (oct == 0) { sm.g.sS[row] = s; if (cb == 0) axo[rc] = ax; }
        }
        __syncthreads();

        int ty = tid >> 5, tx = tid & 31;  // 16 row-quads x 32 col-quads
        float acc[4][4] = {};
#pragma unroll 1
        for (int kt = 0; kt < 16; ++kt) {
            int k0 = kt * 16;
            if (tid < 256) {
                int ra = tid >> 2, kq = tid & 3;
                int rc = row0 + ra;
                size_t aoff = (size_t)(rc >> 5) * strideB + (size_t)(rc & 31) * 256 + k0 + kq * 4;
                float4 av = *(const float4*)&A[aoff];
                float sc = sm.g.sS[ra];
                sm.g.As[kq * 4 + 0][ra] = av.x * sc;
                sm.g.As[kq * 4 + 1][ra] = av.y * sc;
                sm.g.As[kq * 4 + 2][ra] = av.z * sc;
                sm.g.As[kq * 4 + 3][ra] = av.w * sc;
            }
            {
                int kb = tid >> 5, cq = tid & 31;
                float4 bv = *(const float4*)&Bt[(size_t)(k0 + kb) * 768 + col0 + cq * 4];
                *(float4*)&sm.g.Bs[kb][cq * 4] = bv;
            }
            __syncthreads();
#pragma unroll
            for (int kk = 0; kk < 16; ++kk) {
                float4 a4 = *(const float4*)&sm.g.As[kk][ty * 4];
                float4 b4 = *(const float4*)&sm.g.Bs[kk][tx * 4];
                float aa[4] = {a4.x, a4.y, a4.z, a4.w};
                float bb[4] = {b4.x, b4.y, b4.z, b4.w};
#pragma unroll
                for (int i = 0; i < 4; ++i)
#pragma unroll
                    for (int j = 0; j < 4; ++j)
                        acc[i][j] = fmaf(aa[i], bb[j], acc[i][j]);
            }
            __syncthreads();
        }
#pragma unroll
        for (int i = 0; i < 4; ++i) {
            size_t row = (size_t)row0 + ty * 4 + i;
            *(float4*)&C[row * 768 + col0 + tx * 4] =
                make_float4(acc[i][0], acc[i][1], acc[i][2], acc[i][3]);
        }
        return;
    }

    // ==================== SCAN role ====================
    const int slot = bid >> 6, bb = bid & 63;
    const float* mx      = a.s_mx[slot];
    const float* axp     = a.s_ax[slot];
    const uint32_t* w1pk = a.s_w1[slot];
    const uint32_t* whh2g= a.s_whh[slot];
    const float* bias    = a.s_bias[slot];
    float* hcar          = a.s_hcar[slot];
    float* outbase       = a.s_out[slot];
    const long long stride_b = a.s_sb[slot];
    const long long stride_t = a.s_st[slot];

    const int lane = tid & 63, wave = tid >> 6;
    const int p = wave * 32 + (lane & 31), ph = lane >> 5;

    // stage-2 weights -> LDS: LINEAR uint4 copy (prep2 pre-ordered)
    {
        const uint4* s4 = (const uint4*)whh2g;
#pragma unroll
        for (int i = 0; i < 16; ++i)
            sm.s.whhS[i * 512 + tid] = s4[i * 512 + tid];
    }
    // stage-1 weights -> registers (128 u32 = 256 f16)
    uint32_t w1[128];
    {
        const uint4* wp = (const uint4*)w1pk;  // [32][512] uint4
#pragma unroll
        for (int r4 = 0; r4 < 32; ++r4) {
            uint4 v = wp[r4 * 512 + tid];
            w1[4 * r4 + 0] = v.x; w1[4 * r4 + 1] = v.y;
            w1[4 * r4 + 2] = v.z; w1[4 * r4 + 3] = v.w;
        }
    }

    const float* uxpb = mx + (size_t)bb * Tc * 768;

    // ---- inline mscale prologue: per (t,g): f, uxn, uxb into LDS ----
    {
        const int UPW = (Tc * 3) >> 3;  // 12 units per wave
#pragma unroll 1
        for (int i = 0; i < UPW; ++i) {
            int u = wave * UPW + i;
            int tt = u / 3, g = u - 3 * tt;
            const float* rowp = uxpb + (size_t)tt * 768 + g * 256 + lane * 4;
            float4 v = *(const float4*)rowp;
            float4 b4 = *(const float4*)&bias[g * 256 + lane * 4];
            float n2 = wsum63_(v.x * v.x + v.y * v.y + v.z * v.z + v.w * v.w);
            float vb = wsum63_(v.x * b4.x + v.y * b4.y + v.z * b4.z + v.w * b4.w);
            if (lane == 63) {
                float nt = sqrtf(n2);
                float mxn = fmaxf(nt, MINN);
                float arg = mxn * axp[bb * Tc + tt];
                float tk = tan_k_(arg, sk, rsk);
                float f = tk * frcp_(mxn);
                ((float*)&sm.s.fS4[tt])[g] = f;
                ((float*)&sm.s.unS4[tt])[g] = tk * (nt * frcp_(mxn));
                ((float*)&sm.s.ubS4[tt])[g] = f * vb;
            }
        }
    }

    const float br = bias[p], bh = bias[256 + p], bz = bias[512 + p];
    float h = hcar[bb * 256 + p];
    __syncthreads();  // whhS + fS/un/ub ready
    float v4[4] = {br * br, bh * bh, bz * bz, h * h};
    bredX<4>(v4, sm.s.redbuf[0], tid);
    const float bn2r = 0.5f * v4[0], bn2h = 0.5f * v4[1], bn2z = 0.5f * v4[2];
    float S_h2 = 0.5f * v4[3];

    float* myout = outbase + (size_t)bb * stride_b;

    // prefetch step 0 raw ux
    float prawr = uxpb[p], prawh = uxpb[256 + p], prawz = uxpb[512 + p];

    for (int t = 0; t < Tc; ++t) {
        const float4 ff = sm.s.fS4[t];
        const float4 uu = sm.s.unS4[t];
        const float4 ub = sm.s.ubS4[t];
        const float uxr = prawr * ff.x, uxh = prawh * ff.y, uxz = prawz * ff.z;
        const float unr = uu.x, unh = uu.y, unz = uu.z;
        const float S_ubr = ub.x, S_ubh = ub.y, S_ubz = ub.z;

        // ---- expmap0(h): publish hy EARLY, then finish scalar chain ----
        float hn = sqrtf(S_h2);
        float nrm = fmaxf(hn, MINN);
        float tk0 = tan_k_(nrm, sk, rsk);
        float chy = tk0 * frcp_(nrm);
        float hy = chy * h;
        if (ph == 0) ((half_t*)sm.s.hy2S)[p] = (half_t)hy;  // early publish
        float Shy2 = chy * chy * S_h2;
        float xnh = fmaxf(tk0 * (hn * frcp_(nrm)), MINN);
        float axh = artan_k_(xnh, sk, rsk) * frcp_(xnh);
        __syncthreads();  // B1: hy ready

        // prefetch next step raw ux (hidden under matvec + reductions)
        if (t + 1 < Tc) {
            const float* uxp2 = uxpb + (size_t)(t + 1) * 768;
            prawr = uxp2[p]; prawh = uxp2[256 + p]; prawz = uxp2[512 + p];
        }

        // ---- stage-1 matvec (r,z), half-split, 4-deep accumulators ----
        float prA[4] = {0.f, 0.f, 0.f, 0.f};
        float pzA[4] = {0.f, 0.f, 0.f, 0.f};
        {
            const uint4* hp = (const uint4*)sm.s.hy2S + ph * 16;
#pragma unroll
            for (int c4 = 0; c4 < 4; ++c4) {
                uint32_t hv[16];
#pragma unroll
                for (int u = 0; u < 4; ++u) {
                    uint4 v = hp[c4 * 4 + u];
                    hv[4 * u + 0] = v.x; hv[4 * u + 1] = v.y;
                    hv[4 * u + 2] = v.z; hv[4 * u + 3] = v.w;
                }
#pragma unroll
                for (int m = 0; m < 16; ++m) {
                    prA[c4] = dot2acc(w1[c4 * 16 + m], hv[m], prA[c4]);
                    pzA[c4] = dot2acc(w1[64 + c4 * 16 + m], hv[m], pzA[c4]);
                }
            }
        }
        float pr = (prA[0] + prA[1]) + (prA[2] + prA[3]);
        float pz = (pzA[0] + pzA[1]) + (pzA[2] + pzA[3]);
        const float mr = pr + __shfl_xor(pr, 32, 64);
        const float mz = pz + __shfl_xor(pz, 32, 64);

        float vr[8] = {mr * mr, mz * mz, mr * uxr, mz * uxz,
                       mr * br, mz * bz, h * uxh, h * bh};
        bredX<8>(vr, sm.s.redbuf[0], tid);
        const float S_mr2 = 0.5f * vr[0], S_mz2 = 0.5f * vr[1];
        const float S_mru = 0.5f * vr[2], S_mzu = 0.5f * vr[3];
        const float S_mrb = 0.5f * vr[4], S_mzb = 0.5f * vr[5];
        const float S_huxh = 0.5f * vr[6], S_hbh = 0.5f * vr[7];

        // ---- gates r,z: ONE chain per lane; ph=0 -> r, ph=1 -> z ----
        const float m_   = ph ? mz    : mr;
        const float S2_  = ph ? S_mz2 : S_mr2;
        const float Su_  = ph ? S_mzu : S_mru;
        const float Sb_  = ph ? S_mzb : S_mrb;
        const float Sub_ = ph ? S_ubz : S_ubr;
        const float bn2_ = ph ? bn2z  : bn2r;
        const float un_  = ph ? unz   : unr;
        const float ux_  = ph ? uxz   : uxr;
        const float b_   = ph ? bz    : br;
        float g_own;
        {
            float mxn = fmaxf(sqrtf(S2_), MINN);
            float tk = tan_k_(mxn * axh, sk, rsk);
            float f = tk * frcp_(mxn);
            float x2 = f * f * S2_, y2 = un_ * un_, xy = f * Su_;
            float aq = 1.f - 2.f * k * xy - k * y2;
            float bq = 1.f + k * x2;
            float rd = frcp_(fmaxf(1.f - 2.f * k * xy + k * k * x2 * y2, MINN));
            float c1 = (aq * f * m_ + bq * ux_) * rd;
            float Sc12 = (aq * aq * x2 + 2.f * aq * bq * xy + bq * bq * y2) * (rd * rd);
            float Sc1b = (aq * f * Sb_ + bq * Sub_) * rd;
            float g = 1.f - 2.f * k * Sc1b - k * bn2_;
            float dl = 1.f + k * Sc12;
            float re = frcp_(fmaxf(1.f - 2.f * k * Sc1b + k * k * Sc12 * bn2_, MINN));
            float c2 = (g * c1 + dl * b_) * re;
            float Sc22 = (g * g * Sc12 + 2.f * g * dl * Sc1b + dl * dl * bn2_) * (re * re);
            float yn = fmaxf(sqrtf(Sc22), MINN);
            float lg = artan_k_(yn, sk, rsk) * frcp_(yn) * c2;
            g_own = sigm_(lg);
        }
        const float g_oth = __shfl_xor(g_own, 32, 64);
        const float r_t = ph ? g_oth : g_own;
        const float z_t = ph ? g_own : g_oth;

        // ---- rh: publish UNSCALED wx; merge S_wx2 reduction into same barrier ----
        float wx = r_t * hy;
        if (ph == 0) ((half_t*)sm.s.rh2S)[p] = (half_t)wx;
        {
            float s1v = wsum63_(wx * wx);
            if (lane == 63) sm.s.redbuf[1][wave] = s1v;
        }
        __syncthreads();  // B_B: rh/wx ready + partials ready

        float part1 = gsum8_(sm.s.redbuf[1][lane & 7]);
        const float S_wx2 = 0.5f * rdlane_(part1, 7);
        float wxt = sqrtf(S_wx2);
        float wxn = fmaxf(wxt, MINN);
        float tkw = tan_k_(wxn * axh, sk, rsk);
        float fw = tkw * frcp_(wxn);      // rh = fw * wx (fw block scalar)
        float rhn = tkw * (wxt * frcp_(wxn));

        // ---- stage-2 matvec (h gate), half-split, 4-deep accumulators ----
        float qA[4] = {0.f, 0.f, 0.f, 0.f};
        {
            const uint4* rp = (const uint4*)sm.s.rh2S + ph * 16;
#pragma unroll
            for (int u = 0; u < 16; ++u) {
                uint4 wv = sm.s.whhS[(ph * 16 + u) * 256 + p];
                uint4 rv = rp[u];
                int s = u >> 2;
                qA[s] = dot2acc(wv.x, rv.x, qA[s]);
                qA[s] = dot2acc(wv.y, rv.y, qA[s]);
                qA[s] = dot2acc(wv.z, rv.z, qA[s]);
                qA[s] = dot2acc(wv.w, rv.w, qA[s]);
            }
        }
        float qq = (qA[0] + qA[1]) + (qA[2] + qA[3]);
        const float mh = fw * (qq + __shfl_xor(qq, 32, 64));

        float v4b[4] = {mh * mh, mh * uxh, mh * bh, hy * mh};
        bredX<4>(v4b, sm.s.redbuf[0], tid);
        const float S_mh2 = 0.5f * v4b[0], S_mhu = 0.5f * v4b[1];
        const float S_mhb = 0.5f * v4b[2], S_hymh = 0.5f * v4b[3];

        float wz, Sdelta2;
        {
            float xnrh = fmaxf(rhn, MINN);
            float axrh = artan_k_(xnrh, sk, rsk) * frcp_(xnrh);
            float mxn = fmaxf(sqrtf(S_mh2), MINN);
            float tk = tan_k_(mxn * axrh, sk, rsk);
            float f = tk * frcp_(mxn);
            float x2 = f * f * S_mh2, y2 = unh * unh, xy = f * S_mhu;
            float aq = 1.f - 2.f * k * xy - k * y2;
            float bq = 1.f + k * x2;
            float rd = frcp_(fmaxf(1.f - 2.f * k * xy + k * k * x2 * y2, MINN));
            float c1 = (aq * f * mh + bq * uxh) * rd;
            float Sc12 = (aq * aq * x2 + 2.f * aq * bq * xy + bq * bq * y2) * (rd * rd);
            float Sc1b = (aq * f * S_mhb + bq * S_ubh) * rd;
            float S_hyc1 = (aq * f * S_hymh + bq * chy * S_huxh) * rd;
            float g = 1.f - 2.f * k * Sc1b - k * bn2h;
            float dl = 1.f + k * Sc12;
            float re = frcp_(fmaxf(1.f - 2.f * k * Sc1b + k * k * Sc12 * bn2h, MINN));
            float htl = (g * c1 + dl * bh) * re;
            float Shtl2 = (g * g * Sc12 + 2.f * g * dl * Sc1b + dl * dl * bn2h) * (re * re);
            float S_hyhtl = (g * S_hyc1 + dl * chy * S_hbh) * re;
            // delta = mobius_add(-hy, htl): xy_d = -S_hyhtl
            float ad = 1.f + 2.f * k * S_hyhtl - k * Shtl2;
            float bd = 1.f + k * Shy2;
            float rdd = frcp_(fmaxf(1.f + 2.f * k * S_hyhtl + k * k * Shy2 * Shtl2, MINN));
            float delta = (ad * (-hy) + bd * htl) * rdd;
            Sdelta2 = (ad * ad * Shy2 - 2.f * ad * bd * S_hyhtl + bd * bd * Shtl2) * (rdd * rdd);
            wz = z_t * delta;
        }
        float v2[2] = {wz * wz, hy * wz};
        bredX<2>(v2, sm.s.redbuf[1], tid);
        const float S_wz2 = 0.5f * v2[0], S_hywz = 0.5f * v2[1];

        {
            float dnc = fmaxf(sqrtf(Sdelta2), MINN);
            float axd = artan_k_(dnc, sk, rsk) * frcp_(dnc);
            float wzt = sqrtf(S_wz2);
            float wznc = fmaxf(wzt, MINN);
            float tkzd = tan_k_(wznc * axd, sk, rsk);
            float fz = tkzd * frcp_(wznc);
            float zd = fz * wz;
            float zdn2 = fz * fz * S_wz2;
            float S_hyzd = fz * S_hywz;
            float an = 1.f - 2.f * k * S_hyzd - k * zdn2;
            float bn_ = 1.f + k * Shy2;
            float rdn = frcp_(fmaxf(1.f - 2.f * k * S_hyzd + k * k * Shy2 * zdn2, MINN));
            float hnew = (an * hy + bn_ * zd) * rdn;
            float Shnew2 = (an * an * Shy2 + 2.f * an * bn_ * S_hyzd + bn_ * bn_ * zdn2) * (rdn * rdn);
            float yn = fmaxf(sqrtf(Shnew2), MINN);
            float ayn = artan_k_(yn, sk, rsk) * frcp_(yn);
            float outv = ayn * hnew;
            if (ph == 0) myout[(size_t)t * stride_t + p] = outv;
            h = outv;
            S_h2 = ayn * ayn * Shnew2;  // carried
        }
    }
    if (ph == 0) hcar[bb * 256 + p] = h;
}

// ---------- host launcher ----------
extern "C" void kernel_launch(void* const* d_in, const int* in_sizes, int n_in,
                              void* d_out, int out_size, void* d_ws, size_t ws_size,
                              hipStream_t stream) {
    const float* x    = (const float*)d_in[0];
    const float* kptr = (const float*)d_in[1];
    const float* h0   = (const float*)d_in[2];
    const float* wih0 = (const float*)d_in[3];
    const float* whh0 = (const float*)d_in[4];
    const float* b0   = (const float*)d_in[5];
    const float* wih1 = (const float*)d_in[6];
    const float* whh1 = (const float*)d_in[7];
    const float* b1   = (const float*)d_in[8];
    float* out = (float*)d_out;
    float* ws  = (float*)d_ws;

    const int B = 64, T = 1024, H = 256;
    const int CT = 32, NC = 32;
    const int RC = B * CT;        // 2048 chunk rows
    const int GBLK = (RC / 64) * 6;  // 192 gemm blocks per slot

    float* wt_ih0 = ws;
    float* wt_ih1 = wt_ih0 + 196608;
    uint32_t* w1pk0  = (uint32_t*)(wt_ih1 + 196608);
    uint32_t* w1pk1  = w1pk0 + 65536;
    uint32_t* whh2g0 = w1pk1 + 65536;
    uint32_t* whh2g1 = whh2g0 + 32768;
    float* hcar  = (float*)(whh2g1 + 32768);      // 32768
    float* ax0b_[2], *ax1b_[2], *out0c_[2], *mx0_[2], *mx1_[2];
    {
        float* cur = hcar + 32768;
        ax0b_[0] = cur; cur += RC;
        ax0b_[1] = cur; cur += RC;
        ax1b_[0] = cur; cur += RC;
        ax1b_[1] = cur; cur += RC;
        out0c_[0] = cur; cur += (size_t)RC * H;
        out0c_[1] = cur; cur += (size_t)RC * H;
        mx0_[0] = cur; cur += (size_t)RC * 768;
        mx0_[1] = cur; cur += (size_t)RC * 768;
        mx1_[0] = cur; cur += (size_t)RC * 768;
        mx1_[1] = cur; cur += (size_t)RC * 768;
    }
    float* hcar0 = hcar;
    float* hcar1 = hcar + (size_t)B * H;

    dim3 blk(256);
    kt_transpose<<<dim3(1536), blk, 0, stream>>>(wih0, wih1, wt_ih0, wt_ih1);
    kt_prep1<<<dim3(512), blk, 0, stream>>>(whh0, whh1, w1pk0, w1pk1);
    kt_prep2<<<dim3(256), blk, 0, stream>>>(whh0, whh1, whh2g0, whh2g1);
    kt_init<<<dim3(128), blk, 0, stream>>>(h0, hcar);

    // pre-launch: gemm L0 chunk 0 only
    {
        MegaArgs a{};
        a.nscan = 0; a.ngemm = 1; a.Tc = CT; a.kptr = kptr;
        a.g_A[0] = x; a.g_sB[0] = (long long)T * 256; a.g_Bt[0] = wt_ih0;
        a.g_C[0] = mx0_[0]; a.g_ax[0] = ax0b_[0]; a.g_mode[0] = 0;
        kt_mega<<<dim3(GBLK), dim3(512), 0, stream>>>(a);
    }

    for (int c = 0; c <= NC + 1; ++c) {
        MegaArgs a{};
        int ns = 0, ng = 0;
        if (c <= NC - 1) {  // scan L0 chunk c
            a.s_mx[ns] = mx0_[c & 1]; a.s_ax[ns] = ax0b_[c & 1];
            a.s_w1[ns] = w1pk0; a.s_whh[ns] = whh2g0;
            a.s_bias[ns] = b0; a.s_hcar[ns] = hcar0;
            a.s_out[ns] = out0c_[c & 1];
            a.s_sb[ns] = (long long)CT * 256; a.s_st[ns] = 256;
            ns++;
        }
        int d = c - 2;
        if (d >= 0 && d <= NC - 1) {  // scan L1 chunk d
            a.s_mx[ns] = mx1_[d & 1]; a.s_ax[ns] = ax1b_[d & 1];
            a.s_w1[ns] = w1pk1; a.s_whh[ns] = whh2g1;
            a.s_bias[ns] = b1; a.s_hcar[ns] = hcar1;
            a.s_out[ns] = out + (size_t)d * CT * B * H;
            a.s_sb[ns] = 256; a.s_st[ns] = (long long)B * H;
            ns++;
        }
        int e = c + 1;
        if (e <= NC - 1) {  // gemm L0 chunk e
            a.g_A[ng] = x + (size_t)e * CT * 256; a.g_sB[ng] = (long long)T * 256;
            a.g_Bt[ng] = wt_ih0; a.g_C[ng] = mx0_[e & 1];
            a.g_ax[ng] = ax0b_[e & 1]; a.g_mode[ng] = 0;
            ng++;
        }
        int f = c - 1;
        if (f >= 0 && f <= NC - 1) {  // gemm L1 chunk f
            a.g_A[ng] = out0c_[f & 1]; a.g_sB[ng] = (long long)CT * 256;
            a.g_Bt[ng] = wt_ih1; a.g_C[ng] = mx1_[f & 1];
            a.g_ax[ng] = ax1b_[f & 1]; a.g_mode[ng] = 1;
            ng++;
        }
        a.nscan = ns; a.ngemm = ng; a.Tc = CT; a.kptr = kptr;
        int nb = ns * 64 + ng * GBLK;
        if (nb > 0)
            kt_mega<<<dim3(nb), dim3(512), 0, stream>>>(a);
    }
    kt_final<<<dim3(128), blk, 0, stream>>>(hcar, out + (size_t)T * B * H);
}